// Round 7
// baseline (402.801 us; speedup 1.0000x reference)
//
#include <hip/hip_runtime.h>
#include <hip/hip_bf16.h>
#include <math.h>

#define NEG 0.2f
#define BNEPS 1e-5f
#define NGRAPH 64
#define SCAN_CHUNK 2048

typedef short bf16x8 __attribute__((ext_vector_type(8)));            // 8 bf16 (4 VGPRs)
typedef float f32x4  __attribute__((ext_vector_type(4)));            // MFMA accumulator
typedef float f32x2  __attribute__((ext_vector_type(2)));            // fp8 cvt result

__device__ __forceinline__ float bf2f(unsigned short u) {
    return __uint_as_float(((unsigned)u) << 16);
}
__device__ __forceinline__ short f2bf(float f) {
    return (short)__bfloat16_as_ushort(__float2bfloat16(f));
}
__device__ __forceinline__ unsigned char f2fp8(float f) {
    // OCP e4m3 on gfx950; pack (f,f) and take low byte
    int pk = __builtin_amdgcn_cvt_pk_fp8_f32(f, f, 0, false);
    return (unsigned char)(pk & 0xFF);
}

// ---------- init: zero counts, pool accs; precompute uv (L1/L2 logit vecs),
// u0/v0 (L0 logit vecs), Wcomb = blockdiag(conv0_W) @ pre0_W, bias_comb ----------
__global__ __launch_bounds__(256)
void init_kernel(const int* __restrict__ batch, int N,
                 int* __restrict__ counts,
                 float* __restrict__ hg_acc, float* __restrict__ wsum_acc,
                 const float* __restrict__ convs_W,
                 const float* __restrict__ convs_as, const float* __restrict__ convs_ad,
                 const float* __restrict__ conv0_W,
                 const float* __restrict__ conv0_as, const float* __restrict__ conv0_ad,
                 const float* __restrict__ conv0_b,
                 const float* __restrict__ pre0_W, const float* __restrict__ pre0_b,
                 float* __restrict__ uv,
                 float* __restrict__ u0, float* __restrict__ v0,
                 float* __restrict__ Wcomb, float* __restrict__ bias_comb)
{
    int idx = blockIdx.x * 256 + threadIdx.x;
    for (int i = idx; i < N; i += gridDim.x * 256) counts[i] = 0;
    if (blockIdx.x == 0) {
        int t = threadIdx.x;
        for (int i = t; i < NGRAPH * 64; i += 256) hg_acc[i] = 0.f;
        if (t < NGRAPH) wsum_acc[t] = 0.f;
    }
    if (blockIdx.x == 1) {
        // uv layout: u[2][4][64] then v[2][4][64]
        int t = threadIdx.x;
        int h = t >> 6, k = t & 63;
        for (int i = 0; i < 2; ++i) {
            const float* Wr  = convs_W + (size_t)i * 64 * 256 + k * 256 + h * 64;
            const float* av  = convs_as + i * 256 + h * 64;
            const float* dv  = convs_ad + i * 256 + h * 64;
            float su = 0.f, sv = 0.f;
            for (int c = 0; c < 64; ++c) { su += Wr[c] * av[c]; sv += Wr[c] * dv[c]; }
            uv[i * 256 + h * 64 + k]       = su;
            uv[512 + i * 256 + h * 64 + k] = sv;
        }
        if (t < 64) {
            float s = pre0_b[t];
            for (int c = 0; c < 256; ++c) s += conv0_b[c] * pre0_W[c * 64 + t];
            bias_comb[t] = s;
        }
    }
    if (blockIdx.x == 2) {
        // u0[h*128+k] = sum_c conv0_W[k, h*64+c]*a_src[h,c];  v0 likewise with a_dst
        int t = threadIdx.x;
        for (int e = t; e < 512; e += 256) {
            int h = e >> 7, k = e & 127;
            const float* Wr = conv0_W + (size_t)k * 256 + h * 64;
            const float* av = conv0_as + h * 64;
            const float* dv = conv0_ad + h * 64;
            float su = 0.f, sv = 0.f;
            for (int c = 0; c < 64; ++c) { su += Wr[c] * av[c]; sv += Wr[c] * dv[c]; }
            u0[e] = su; v0[e] = sv;
        }
    }
    if (blockIdx.x >= 3 && blockIdx.x < 11) {
        // Wcomb[(h*128+k)*64 + c'] = sum_c conv0_W[k, h*64+c] * pre0_W[h*64+c, c']
        int base = (blockIdx.x - 3) * 4096 + threadIdx.x * 16;
        for (int i = 0; i < 16; ++i) {
            int e = base + i;
            int hk = e >> 6, cp = e & 63;
            int h = hk >> 7, k = hk & 127;
            const float* Wr = conv0_W + (size_t)k * 256 + h * 64;
            const float* Pr = pre0_W + (size_t)h * 64 * 64 + cp;
            float s = 0.f;
            for (int c = 0; c < 64; ++c) s += Wr[c] * Pr[c * 64];
            Wcomb[(size_t)hk * 64 + cp] = s;
        }
    }
}

// ---------- x -> fp8 cast + layer-0 attention logits (as0 = x·u0[h], ad0 = x·v0[h]) ----------
__global__ __launch_bounds__(256)
void cast_x_kernel(const float* __restrict__ x,
                   const float* __restrict__ u0, const float* __restrict__ v0,
                   unsigned char* __restrict__ x8,
                   float* __restrict__ as_out, float* __restrict__ ad_out, int N)
{
    int node = (blockIdx.x * blockDim.x + threadIdx.x) >> 6;
    int lane = threadIdx.x & 63;
    if (node >= N) return;
    float2 xv = *(const float2*)(x + (size_t)node * 128 + lane * 2);
    int pk = __builtin_amdgcn_cvt_pk_fp8_f32(xv.x, xv.y, 0, false);
    *(unsigned short*)(x8 + (size_t)node * 128 + lane * 2) = (unsigned short)(pk & 0xFFFF);
    float p[8];
    #pragma unroll
    for (int h = 0; h < 4; ++h) {
        p[h]     = xv.x * u0[h * 128 + lane * 2] + xv.y * u0[h * 128 + lane * 2 + 1];
        p[4 + h] = xv.x * v0[h * 128 + lane * 2] + xv.y * v0[h * 128 + lane * 2 + 1];
    }
    #pragma unroll
    for (int j = 0; j < 8; ++j)
        #pragma unroll
        for (int o = 1; o < 64; o <<= 1) p[j] += __shfl_xor(p[j], o);
    if (lane == 0) {
        #pragma unroll
        for (int h = 0; h < 4; ++h) {
            as_out[node * 4 + h] = p[h];
            ad_out[node * 4 + h] = p[4 + h];
        }
    }
}

// ---------- layer-0 aggregation: gather 128B fp8 x rows, 4-head weighted means ----------
// lane (h=l>>4, li=l&15) owns channels li*8..+7 for head h. Output z0[n, h*128+k] bf16.
__global__ __launch_bounds__(256)
void aggregate_z0(const int* __restrict__ rowptr, const int* __restrict__ csr_src,
                  const float* __restrict__ as_n, const float* __restrict__ ad_n,
                  const unsigned char* __restrict__ x8,
                  unsigned short* __restrict__ zout, int N)
{
    int node = (blockIdx.x * blockDim.x + threadIdx.x) >> 6;
    int lane = threadIdx.x & 63;
    if (node >= N) return;
    int h = lane >> 4, li = lane & 15, grp = lane & 48;
    int e0 = rowptr[node], e1 = rowptr[node + 1];
    float adh = ad_n[node * 4 + h];
    unsigned laneoff = (unsigned)(li * 8);     // 8 fp8 bytes within the 128B row

    float acc[8];
    #pragma unroll
    for (int j = 0; j < 8; ++j) acc[j] = 0.f;
    float wsum = 0.f;

#define ACC_EDGE(wk, xa) {                                                \
        f32x2 l0 = __builtin_amdgcn_cvt_pk_f32_fp8((int)(xa).x, false);   \
        f32x2 h0 = __builtin_amdgcn_cvt_pk_f32_fp8((int)(xa).x, true);    \
        f32x2 l1 = __builtin_amdgcn_cvt_pk_f32_fp8((int)(xa).y, false);   \
        f32x2 h1 = __builtin_amdgcn_cvt_pk_f32_fp8((int)(xa).y, true);    \
        acc[0] += (wk) * l0.x; acc[1] += (wk) * l0.y;                     \
        acc[2] += (wk) * h0.x; acc[3] += (wk) * h0.y;                     \
        acc[4] += (wk) * l1.x; acc[5] += (wk) * l1.y;                     \
        acc[6] += (wk) * h1.x; acc[7] += (wk) * h1.y; }

    for (int base = e0; base < e1; base += 16) {
        int cnt = e1 - base; if (cnt > 16) cnt = 16;
        int s = 0; float w = 0.f;
        if (li < cnt) {
            s = csr_src[base + li];
            float l = as_n[s * 4 + h] + adh;
            l = fmaxf(l, NEG * l);
            w = __expf(l);
        }
        int k = 0;
        for (; k + 3 < cnt; k += 4) {
            float w0 = __shfl(w, grp + k),     w1 = __shfl(w, grp + k + 1);
            float w2 = __shfl(w, grp + k + 2), w3 = __shfl(w, grp + k + 3);
            int s0 = __shfl(s, grp + k),       s1 = __shfl(s, grp + k + 1);
            int s2 = __shfl(s, grp + k + 2),   s3 = __shfl(s, grp + k + 3);
            uint2 a0 = *(const uint2*)(x8 + ((size_t)(unsigned)s0 * 128u + laneoff));
            uint2 a1 = *(const uint2*)(x8 + ((size_t)(unsigned)s1 * 128u + laneoff));
            uint2 a2 = *(const uint2*)(x8 + ((size_t)(unsigned)s2 * 128u + laneoff));
            uint2 a3 = *(const uint2*)(x8 + ((size_t)(unsigned)s3 * 128u + laneoff));
            ACC_EDGE(w0, a0); ACC_EDGE(w1, a1); ACC_EDGE(w2, a2); ACC_EDGE(w3, a3);
            wsum += (w0 + w1) + (w2 + w3);
        }
        for (; k < cnt; ++k) {
            float wk = __shfl(w, grp + k);
            int sk = __shfl(s, grp + k);
            uint2 av = *(const uint2*)(x8 + ((size_t)(unsigned)sk * 128u + laneoff));
            ACC_EDGE(wk, av);
            wsum += wk;
        }
    }
#undef ACC_EDGE

    float rw = 1.f / wsum;
    bf16x8 pk;
    #pragma unroll
    for (int j = 0; j < 8; ++j) pk[j] = f2bf(acc[j] * rw);
    *(bf16x8*)(zout + (size_t)node * 512 + h * 128 + li * 8) = pk;
}

// ---------- MFMA bf16 GEMM, Nc=64, K chunked in <=256 slices ----------
// w_gat=1: W is convs_W (64,256) consumed as Wstack[(h,k),c]=W[k,h*64+c]
// fused epilogue: scale, bias, BN+ELU (mode 1), +resid, fp8 h8 snapshot,
// as/ad logits via u/v (butterfly fold), attentional pooling (block-reduced atomics).
__global__ __launch_bounds__(256)
void gemm_n64_mfma(const void* __restrict__ Araw, int lda, int a_is_bf16,
                   const float* __restrict__ W, int w_gat, int M, int K,
                   const float* __restrict__ bias, float scale,
                   float* __restrict__ C, int ldc, int mode,
                   const float* __restrict__ bn_g, const float* __restrict__ bn_b,
                   const float* __restrict__ bn_m, const float* __restrict__ bn_v,
                   const float* __restrict__ resid, int ldr,
                   unsigned char* __restrict__ h8_out,
                   const float* __restrict__ u, const float* __restrict__ v,
                   float* __restrict__ as_out, float* __restrict__ ad_out,
                   const float* __restrict__ attW, const float* __restrict__ attb,
                   const int* __restrict__ batch,
                   float* __restrict__ hg_acc, float* __restrict__ wsum_acc)
{
    __shared__ short Wt[64 * 264];           // one K<=256 chunk (reused as redbuf)
    int tid  = threadIdx.x;
    int lane = tid & 63, wave = tid >> 6;
    int row0 = blockIdx.x * 64;
    int c15 = lane & 15, q = lane >> 4;

    int row = row0 + wave * 16 + c15;
    bool rok = row < M;

    f32x4 acc[4];
    #pragma unroll
    for (int st = 0; st < 4; ++st) acc[st] = (f32x4){0.f, 0.f, 0.f, 0.f};

    for (int kc = 0; kc < K; kc += 256) {
        int CK = K - kc; if (CK > 256) CK = 256;
        const int KP = CK + 8;
        __syncthreads();
        {
            int n = tid & 63;
            for (int k = tid >> 6; k < CK; k += 4) {
                int kk = kc + k;
                int widx = w_gat ? ((kk & 63) * 256 + (kk >> 6) * 64 + n) : (kk * 64 + n);
                Wt[n * KP + k] = f2bf(W[widx]);
            }
        }
        __syncthreads();

        for (int k0 = 0; k0 < CK; k0 += 32) {
            bf16x8 av;
            if (rok) {
                if (a_is_bf16) {
                    av = *(const bf16x8*)((const unsigned short*)Araw
                                          + (size_t)row * lda + kc + k0 + q * 8);
                } else {
                    const float* ap = (const float*)Araw + (size_t)row * lda + kc + k0 + q * 8;
                    float4 a0 = *(const float4*)ap;
                    float4 a1 = *(const float4*)(ap + 4);
                    av[0] = f2bf(a0.x); av[1] = f2bf(a0.y); av[2] = f2bf(a0.z); av[3] = f2bf(a0.w);
                    av[4] = f2bf(a1.x); av[5] = f2bf(a1.y); av[6] = f2bf(a1.z); av[7] = f2bf(a1.w);
                }
            } else {
                av = (bf16x8){0,0,0,0,0,0,0,0};
            }
            #pragma unroll
            for (int st = 0; st < 4; ++st) {
                bf16x8 bv = *(const bf16x8*)(Wt + (st * 16 + c15) * KP + k0 + q * 8);
                acc[st] = __builtin_amdgcn_mfma_f32_16x16x32_bf16(av, bv, acc[st], 0, 0, 0);
            }
        }
    }

    #pragma unroll
    for (int st = 0; st < 4; ++st) {
        int col = st * 16 + c15;
        float bs = bias ? bias[col] : 0.f;
        float sg = 1.f, sb = 0.f;
        if (mode == 1) {
            sg = bn_g[col] / sqrtf(bn_v[col] + BNEPS);
            sb = bn_b[col] - bn_m[col] * sg;
        }
        #pragma unroll
        for (int r = 0; r < 4; ++r) {
            int orow = row0 + wave * 16 + q * 4 + r;
            if (orow >= M) continue;
            float vvv = acc[st][r] * scale + bs;
            if (mode == 1) {
                vvv = vvv * sg + sb;
                vvv = vvv > 0.f ? vvv : __expf(vvv) - 1.f;
            }
            if (resid) vvv += resid[(size_t)orow * ldr + col];
            acc[st][r] = vvv;
            if (C) C[(size_t)orow * ldc + col] = vvv;
        }
    }

    if (h8_out) {
        #pragma unroll
        for (int r = 0; r < 4; ++r) {
            int orow = row0 + wave * 16 + q * 4 + r;
            if (orow >= M) continue;
            unsigned char* hb = h8_out + (size_t)orow * 64 + c15;
            #pragma unroll
            for (int st = 0; st < 4; ++st)
                hb[st * 16] = f2fp8(acc[st][r]);
        }
    }

    if (u) {
        float uu[4][4], vv2[4][4];
        #pragma unroll
        for (int h = 0; h < 4; ++h)
            #pragma unroll
            for (int st = 0; st < 4; ++st) {
                uu[h][st]  = u[h * 64 + st * 16 + c15];
                vv2[h][st] = v[h * 64 + st * 16 + c15];
            }
        #pragma unroll
        for (int r = 0; r < 4; ++r) {
            int orow = row0 + wave * 16 + q * 4 + r;
            float pv[8];
            #pragma unroll
            for (int h = 0; h < 4; ++h) {
                pv[h]     = acc[0][r] * uu[h][0] + acc[1][r] * uu[h][1]
                          + acc[2][r] * uu[h][2] + acc[3][r] * uu[h][3];
                pv[4 + h] = acc[0][r] * vv2[h][0] + acc[1][r] * vv2[h][1]
                          + acc[2][r] * vv2[h][2] + acc[3][r] * vv2[h][3];
            }
            #pragma unroll
            for (int j = 0; j < 4; ++j) {
                float send = (c15 & 8) ? pv[j] : pv[j + 4];
                float keep = (c15 & 8) ? pv[j + 4] : pv[j];
                pv[j] = keep + __shfl_xor(send, 8);
            }
            #pragma unroll
            for (int j = 0; j < 2; ++j) {
                float send = (c15 & 4) ? pv[j] : pv[j + 2];
                float keep = (c15 & 4) ? pv[j + 2] : pv[j];
                pv[j] = keep + __shfl_xor(send, 4);
            }
            {
                float send = (c15 & 2) ? pv[0] : pv[1];
                float keep = (c15 & 2) ? pv[1] : pv[0];
                pv[0] = keep + __shfl_xor(send, 2);
            }
            pv[0] += __shfl_xor(pv[0], 1);
            if ((c15 & 1) == 0 && orow < M) {
                int jj = c15 >> 1;
                if (jj < 4) as_out[orow * 4 + jj] = pv[0];
                else        ad_out[orow * 4 + (jj - 4)] = pv[0];
            }
        }
    }

    // ---- fused attentional pooling with block-level reduction ----
    if (attW) {
        float sa[4];
        #pragma unroll
        for (int st = 0; st < 4; ++st) sa[st] = attW[st * 16 + c15];
        float ab = attb[0];
        float wrow[4];
        int   grow[4];
        #pragma unroll
        for (int r = 0; r < 4; ++r) {
            int orow = row0 + wave * 16 + q * 4 + r;
            bool ok = orow < M;
            float ps = acc[0][r] * sa[0] + acc[1][r] * sa[1]
                     + acc[2][r] * sa[2] + acc[3][r] * sa[3];
            #pragma unroll
            for (int o = 1; o < 16; o <<= 1) ps += __shfl_xor(ps, o);
            wrow[r] = ok ? __expf(ps + ab) : 0.f;
            grow[r] = ok ? batch[orow] : -1;
        }
        int lastrow = row0 + 63; if (lastrow >= M) lastrow = M - 1;
        int gmin = batch[row0 < M ? row0 : M - 1];
        int gmax = batch[lastrow];
        float* red = (float*)Wt;   // [64][4] col-partials + [4] wsum partials
        __syncthreads();           // all waves done reading Wt
        for (int g = gmin; g <= gmax; ++g) {
            float cs[4] = {0.f, 0.f, 0.f, 0.f};
            float wsl = 0.f;
            #pragma unroll
            for (int r = 0; r < 4; ++r) {
                if (grow[r] == g) {
                    #pragma unroll
                    for (int st = 0; st < 4; ++st) cs[st] += acc[st][r] * wrow[r];
                    wsl += wrow[r];
                }
            }
            #pragma unroll
            for (int st = 0; st < 4; ++st) {
                cs[st] += __shfl_xor(cs[st], 16);
                cs[st] += __shfl_xor(cs[st], 32);
            }
            wsl += __shfl_xor(wsl, 16);
            wsl += __shfl_xor(wsl, 32);
            if (q == 0) {
                #pragma unroll
                for (int st = 0; st < 4; ++st)
                    red[(st * 16 + c15) * 4 + wave] = cs[st];
                if (c15 == 0) red[256 + wave] = wsl;
            }
            __syncthreads();
            if (tid < 64) {
                float vv = red[tid * 4] + red[tid * 4 + 1]
                         + red[tid * 4 + 2] + red[tid * 4 + 3];
                if (vv != 0.f) atomicAdd(&hg_acc[g * 64 + tid], vv);
            } else if (tid == 64) {
                float t = red[256] + red[257] + red[258] + red[259];
                if (t != 0.f) atomicAdd(&wsum_acc[g], t);
            }
            __syncthreads();
        }
    }
}

// ---------- CSR build: histogram over dst ----------
__global__ __launch_bounds__(256)
void hist_kernel(const int* __restrict__ ei, int E, int N, int* __restrict__ counts)
{
    int e = blockIdx.x * blockDim.x + threadIdx.x;
    int Etot = E + N;
    if (e >= Etot) return;
    int d = (e < E) ? ei[E + e] : e - E;
    atomicAdd(&counts[d], 1);
}

// ---------- scan phase 1: per-block partial sums ----------
__global__ __launch_bounds__(256)
void scan_phase1(const int* __restrict__ counts, int N, int* __restrict__ blocksum)
{
    __shared__ int wsum[4];
    int tid = threadIdx.x, lane = tid & 63, wave = tid >> 6;
    int base = blockIdx.x * SCAN_CHUNK;
    int s = 0;
    #pragma unroll
    for (int j = 0; j < SCAN_CHUNK / 256; ++j) {
        int idx = base + tid + j * 256;
        if (idx < N) s += counts[idx];
    }
    #pragma unroll
    for (int o = 32; o; o >>= 1) s += __shfl_xor(s, o);
    if (lane == 0) wsum[wave] = s;
    __syncthreads();
    if (tid == 0) blocksum[blockIdx.x] = wsum[0] + wsum[1] + wsum[2] + wsum[3];
}

// ---------- scan phase 3 (merged with global prefix of block sums) ----------
__global__ __launch_bounds__(256)
void scan_phase3(const int* __restrict__ counts, int N, int nb,
                 const int* __restrict__ blocksum,
                 int* __restrict__ rowptr, int* __restrict__ cursor)
{
    __shared__ int wsum[4];
    __shared__ int pref[64];
    int tid = threadIdx.x, lane = tid & 63, wave = tid >> 6;

    if (wave == 0) {
        int v = (lane < nb) ? blocksum[lane] : 0;
        int incl = v;
        #pragma unroll
        for (int o = 1; o < 64; o <<= 1) {
            int t = __shfl_up(incl, o);
            if (lane >= o) incl += t;
        }
        pref[lane] = incl;
    }
    __syncthreads();
    int boff = blockIdx.x ? pref[blockIdx.x - 1] : 0;
    if (blockIdx.x == 0 && tid == 0) rowptr[N] = pref[nb - 1];

    int start = blockIdx.x * SCAN_CHUNK + tid * 8;
    int v[8];
    int s = 0;
    #pragma unroll
    for (int j = 0; j < 8; ++j) {
        v[j] = (start + j < N) ? counts[start + j] : 0;
        s += v[j];
    }
    int incl = s;
    #pragma unroll
    for (int o = 1; o < 64; o <<= 1) {
        int t = __shfl_up(incl, o);
        if (lane >= o) incl += t;
    }
    if (lane == 63) wsum[wave] = incl;
    __syncthreads();
    int woff = 0;
    #pragma unroll
    for (int w = 0; w < 4; ++w) if (w < wave) woff += wsum[w];
    int run = boff + woff + incl - s;
    #pragma unroll
    for (int j = 0; j < 8; ++j) {
        int idx = start + j;
        if (idx < N) { rowptr[idx] = run; cursor[idx] = run; }
        run += v[j];
    }
}

// ---------- CSR build: scatter ----------
__global__ __launch_bounds__(256)
void scatter_kernel(const int* __restrict__ ei, int E, int N,
                    int* __restrict__ cursor, int* __restrict__ csr_src)
{
    int e = blockIdx.x * blockDim.x + threadIdx.x;
    int Etot = E + N;
    if (e >= Etot) return;
    int s, d;
    if (e < E) { s = ei[e]; d = ei[E + e]; } else { s = d = e - E; }
    int pos = atomicAdd(&cursor[d], 1);
    csr_src[pos] = s;
}

// ---------- layers 1-2 aggregation: 64B fp8 rows, proven mapping ----------
__global__ __launch_bounds__(256)
void aggregate_z(const int* __restrict__ rowptr, const int* __restrict__ csr_src,
                 const float* __restrict__ as_n, const float* __restrict__ ad_n,
                 const unsigned char* __restrict__ h8,
                 unsigned short* __restrict__ zout, int N)
{
    int node = (blockIdx.x * blockDim.x + threadIdx.x) >> 6;
    int lane = threadIdx.x & 63;
    if (node >= N) return;
    int h = lane >> 4, li = lane & 15, grp = lane & 48;
    int e0 = rowptr[node], e1 = rowptr[node + 1];
    float adh = ad_n[node * 4 + h];
    unsigned laneoff = (unsigned)(li * 4);     // 4 fp8 bytes within the 64B row

    float4 acc = make_float4(0.f, 0.f, 0.f, 0.f);
    float wsum = 0.f;

    for (int base = e0; base < e1; base += 16) {
        int cnt = e1 - base; if (cnt > 16) cnt = 16;
        int s = 0; float w = 0.f;
        if (li < cnt) {
            s = csr_src[base + li];
            float l = as_n[s * 4 + h] + adh;
            l = fmaxf(l, NEG * l);
            w = __expf(l);
        }
        int k = 0;
        for (; k + 3 < cnt; k += 4) {
            float w0 = __shfl(w, grp + k),     w1 = __shfl(w, grp + k + 1);
            float w2 = __shfl(w, grp + k + 2), w3 = __shfl(w, grp + k + 3);
            int s0 = __shfl(s, grp + k),       s1 = __shfl(s, grp + k + 1);
            int s2 = __shfl(s, grp + k + 2),   s3 = __shfl(s, grp + k + 3);
            unsigned x0 = *(const unsigned*)(h8 + ((unsigned)s0 * 64u + laneoff));
            unsigned x1 = *(const unsigned*)(h8 + ((unsigned)s1 * 64u + laneoff));
            unsigned x2 = *(const unsigned*)(h8 + ((unsigned)s2 * 64u + laneoff));
            unsigned x3 = *(const unsigned*)(h8 + ((unsigned)s3 * 64u + laneoff));
            f32x2 l0 = __builtin_amdgcn_cvt_pk_f32_fp8((int)x0, false);
            f32x2 h0 = __builtin_amdgcn_cvt_pk_f32_fp8((int)x0, true);
            f32x2 l1 = __builtin_amdgcn_cvt_pk_f32_fp8((int)x1, false);
            f32x2 h1 = __builtin_amdgcn_cvt_pk_f32_fp8((int)x1, true);
            f32x2 l2 = __builtin_amdgcn_cvt_pk_f32_fp8((int)x2, false);
            f32x2 h2 = __builtin_amdgcn_cvt_pk_f32_fp8((int)x2, true);
            f32x2 l3 = __builtin_amdgcn_cvt_pk_f32_fp8((int)x3, false);
            f32x2 h3 = __builtin_amdgcn_cvt_pk_f32_fp8((int)x3, true);
            acc.x += w0 * l0.x; acc.y += w0 * l0.y; acc.z += w0 * h0.x; acc.w += w0 * h0.y;
            acc.x += w1 * l1.x; acc.y += w1 * l1.y; acc.z += w1 * h1.x; acc.w += w1 * h1.y;
            acc.x += w2 * l2.x; acc.y += w2 * l2.y; acc.z += w2 * h2.x; acc.w += w2 * h2.y;
            acc.x += w3 * l3.x; acc.y += w3 * l3.y; acc.z += w3 * h3.x; acc.w += w3 * h3.y;
            wsum += (w0 + w1) + (w2 + w3);
        }
        for (; k < cnt; ++k) {
            float wk = __shfl(w, grp + k);
            int sk = __shfl(s, grp + k);
            unsigned xv = *(const unsigned*)(h8 + ((unsigned)sk * 64u + laneoff));
            f32x2 lo = __builtin_amdgcn_cvt_pk_f32_fp8((int)xv, false);
            f32x2 hi = __builtin_amdgcn_cvt_pk_f32_fp8((int)xv, true);
            acc.x += wk * lo.x; acc.y += wk * lo.y;
            acc.z += wk * hi.x; acc.w += wk * hi.y;
            wsum += wk;
        }
    }

    float rw = 1.f / wsum;
    ushort4 pk;
    pk.x = (unsigned short)f2bf(acc.x * rw);
    pk.y = (unsigned short)f2bf(acc.y * rw);
    pk.z = (unsigned short)f2bf(acc.z * rw);
    pk.w = (unsigned short)f2bf(acc.w * rw);
    *(ushort4*)(zout + (size_t)node * 256 + h * 64 + li * 4) = pk;
}

// ---------- classifier head ----------
__global__ void cls_kernel(const float* __restrict__ hg_acc,
                           const float* __restrict__ wsum_acc,
                           const float* __restrict__ W1, const float* __restrict__ b1,
                           const float* __restrict__ W2, const float* __restrict__ b2,
                           float* __restrict__ out)
{
    int g = blockIdx.x, t = threadIdx.x;  // 32 threads
    __shared__ float z[32];
    __shared__ float h[64];
    float wsum = wsum_acc[g];
    float rw = (wsum > 0.f) ? 1.f / wsum : 0.f;
    h[t] = hg_acc[g * 64 + t] * rw;
    h[t + 32] = hg_acc[g * 64 + t + 32] * rw;
    __syncthreads();
    float acc = b1[t];
    for (int k = 0; k < 64; ++k) acc += h[k] * W1[k * 32 + t];
    z[t] = fmaxf(acc, 0.f);
    __syncthreads();
    if (t < 2) {
        float o = b2[t];
        for (int j = 0; j < 32; ++j) o += z[j] * W2[j * 2 + t];
        out[g * 2 + t] = o;
    }
}

extern "C" void kernel_launch(void* const* d_in, const int* in_sizes, int n_in,
                              void* d_out, int out_size, void* d_ws, size_t ws_size,
                              hipStream_t stream)
{
    const float* x        = (const float*)d_in[0];
    const int*   ei       = (const int*)d_in[1];
    const int*   batch    = (const int*)d_in[2];
    const float* conv0_W  = (const float*)d_in[3];
    const float* conv0_as = (const float*)d_in[4];
    const float* conv0_ad = (const float*)d_in[5];
    const float* conv0_b  = (const float*)d_in[6];
    const float* pre0_W   = (const float*)d_in[7];
    const float* pre0_b   = (const float*)d_in[8];
    const float* convs_W  = (const float*)d_in[9];
    const float* convs_as = (const float*)d_in[10];
    const float* convs_ad = (const float*)d_in[11];
    const float* convs_b  = (const float*)d_in[12];
    const float* bn_g     = (const float*)d_in[13];
    const float* bn_b     = (const float*)d_in[14];
    const float* bn_m     = (const float*)d_in[15];
    const float* bn_v     = (const float*)d_in[16];
    const float* jump_W   = (const float*)d_in[17];
    const float* jump_b   = (const float*)d_in[18];
    const float* att_W    = (const float*)d_in[19];
    const float* att_b    = (const float*)d_in[20];
    const float* cls_W1   = (const float*)d_in[21];
    const float* cls_b1   = (const float*)d_in[22];
    const float* cls_W2   = (const float*)d_in[23];
    const float* cls_b2   = (const float*)d_in[24];
    float* out = (float*)d_out;

    const int N = in_sizes[0] / 128;   // 50000
    const int E = in_sizes[1] / 2;     // 400000
    const int Etot = E + N;
    const int nb = (N + SCAN_CHUNK - 1) / SCAN_CHUNK;   // 25 <= 64

    // workspace layout
    float* ws      = (float*)d_ws;
    unsigned short* z0 = (unsigned short*)ws;               // N*512 shorts (z0 / zbuf)
    float* repsAll = ws + (size_t)N * 256;                  // N*192 f32
    float* as_n    = repsAll + (size_t)N * 192;             // N*4
    float* ad_n    = as_n + (size_t)N * 4;                  // N*4
    float* hg_acc  = ad_n + (size_t)N * 4;                  // 64*64
    float* wsum_acc= hg_acc + NGRAPH * 64;                  // 64
    int*   rowptr  = (int*)(wsum_acc + NGRAPH);             // N+1
    int*   cursor  = rowptr + (N + 1);                      // N
    int*   counts  = cursor + N;                            // N
    int*   csr_src = counts + N;                            // Etot
    int*   blocksum = csr_src + Etot;                       // 64
    float* uv      = (float*)(blocksum + 64);               // 1024
    float* u0      = uv + 1024;                             // 512
    float* v0      = u0 + 512;                              // 512
    float* Wcomb   = v0 + 512;                              // 512*64
    float* bias_comb = Wcomb + 512 * 64;                    // 64
    float* as2     = bias_comb + 64;                        // N*4
    float* ad2     = as2 + (size_t)N * 4;                   // N*4
    unsigned char* x8  = (unsigned char*)(ad2 + (size_t)N * 4);  // N*128 bytes
    unsigned char* h8a = x8 + (size_t)N * 128;              // N*64 bytes
    unsigned char* h8b = h8a + (size_t)N * 64;              // N*64 bytes

    dim3 blk(256);
    int node_wave_blocks = (N + 3) / 4;
    int edge_blocks      = (Etot + 255) / 256;
    int row_blocks       = (N + 63) / 64;

    // ---------------- init (+precompute) + CSR build ----------------
    init_kernel<<<64, blk, 0, stream>>>(batch, N, counts, hg_acc, wsum_acc,
                                        convs_W, convs_as, convs_ad,
                                        conv0_W, conv0_as, conv0_ad, conv0_b,
                                        pre0_W, pre0_b,
                                        uv, u0, v0, Wcomb, bias_comb);
    hist_kernel<<<edge_blocks, blk, 0, stream>>>(ei, E, N, counts);
    scan_phase1<<<nb, blk, 0, stream>>>(counts, N, blocksum);
    scan_phase3<<<nb, blk, 0, stream>>>(counts, N, nb, blocksum, rowptr, cursor);
    scatter_kernel<<<edge_blocks, blk, 0, stream>>>(ei, E, N, cursor, csr_src);

    // ---------------- layer 0 (commuted): cast + gather x + combined GEMM ----------------
    cast_x_kernel<<<node_wave_blocks, blk, 0, stream>>>(x, u0, v0, x8, as_n, ad_n, N);
    aggregate_z0<<<node_wave_blocks, blk, 0, stream>>>(rowptr, csr_src, as_n, ad_n,
                                                       x8, z0, N);
    // h1 = ELU(BN(z0 @ Wcomb + bias_comb)); fused: h8a snapshot + layer-1 as/ad logits
    gemm_n64_mfma<<<row_blocks, blk, 0, stream>>>(
        z0, 512, 1, Wcomb, 0, N, 512, bias_comb, 1.f,
        repsAll, 192, 1, bn_g, bn_b, bn_m, bn_v,
        nullptr, 0, h8a, uv, uv + 512, as_n, ad_n,
        nullptr, nullptr, nullptr, nullptr, nullptr);

    // ---------------- layer 1 ----------------
    aggregate_z<<<node_wave_blocks, blk, 0, stream>>>(rowptr, csr_src, as_n, ad_n,
                                                      h8a, z0, N);
    gemm_n64_mfma<<<row_blocks, blk, 0, stream>>>(
        z0, 256, 1, convs_W, 1, N, 256, convs_b, 0.25f,
        repsAll + 64, 192, 1, bn_g + 64, bn_b + 64, bn_m + 64, bn_v + 64,
        repsAll, 192, h8b, uv + 256, uv + 512 + 256, as2, ad2,
        nullptr, nullptr, nullptr, nullptr, nullptr);

    // ---------------- layer 2 ----------------
    aggregate_z<<<node_wave_blocks, blk, 0, stream>>>(rowptr, csr_src, as2, ad2,
                                                      h8b, z0, N);
    gemm_n64_mfma<<<row_blocks, blk, 0, stream>>>(
        z0, 256, 1, convs_W + (size_t)64 * 256, 1, N, 256, convs_b + 64, 0.25f,
        repsAll + 128, 192, 1, bn_g + 128, bn_b + 128, bn_m + 128, bn_v + 128,
        repsAll + 64, 192, nullptr, nullptr, nullptr, nullptr, nullptr,
        nullptr, nullptr, nullptr, nullptr, nullptr);

    // ---------------- JK projection + fused attentional pooling ----------------
    gemm_n64_mfma<<<row_blocks, blk, 0, stream>>>(
        repsAll, 192, 0, jump_W, 0, N, 192, jump_b, 1.f,
        nullptr, 64, 0, nullptr, nullptr, nullptr, nullptr,
        nullptr, 0, nullptr, nullptr, nullptr, nullptr, nullptr,
        att_W, att_b, batch, hg_acc, wsum_acc);

    // ---------------- classifier ----------------
    cls_kernel<<<NGRAPH, 32, 0, stream>>>(hg_acc, wsum_acc, cls_W1, cls_b1,
                                          cls_W2, cls_b2, out);
}

// Round 9
// 358.481 us; speedup vs baseline: 1.1236x; 1.1236x over previous
//
#include <hip/hip_runtime.h>
#include <hip/hip_bf16.h>
#include <math.h>

#define NEG 0.2f
#define BNEPS 1e-5f
#define NGRAPH 64
#define SCAN_CHUNK 2048

typedef short bf16x8 __attribute__((ext_vector_type(8)));            // 8 bf16 (4 VGPRs)
typedef float f32x4  __attribute__((ext_vector_type(4)));            // MFMA accumulator
typedef float f32x2  __attribute__((ext_vector_type(2)));            // fp8 cvt result

__device__ __forceinline__ float bf2f(unsigned short u) {
    return __uint_as_float(((unsigned)u) << 16);
}
__device__ __forceinline__ short f2bf(float f) {
    return (short)__bfloat16_as_ushort(__float2bfloat16(f));
}
__device__ __forceinline__ unsigned char f2fp8(float f) {
    // OCP e4m3 on gfx950; pack (f,f) and take low byte
    int pk = __builtin_amdgcn_cvt_pk_fp8_f32(f, f, 0, false);
    return (unsigned char)(pk & 0xFF);
}

// ---------- init: zero counts, pool accs; block 1: u/v = W_h @ att ----------
__global__ __launch_bounds__(256)
void init_kernel(const int* __restrict__ batch, int N,
                 int* __restrict__ counts,
                 float* __restrict__ hg_acc, float* __restrict__ wsum_acc,
                 const float* __restrict__ convs_W,
                 const float* __restrict__ convs_as, const float* __restrict__ convs_ad,
                 float* __restrict__ uv)
{
    int idx = blockIdx.x * 256 + threadIdx.x;
    for (int i = idx; i < N; i += gridDim.x * 256) counts[i] = 0;
    if (blockIdx.x == 0) {
        int t = threadIdx.x;
        for (int i = t; i < NGRAPH * 64; i += 256) hg_acc[i] = 0.f;
        if (t < NGRAPH) wsum_acc[t] = 0.f;
    }
    if (blockIdx.x == 1) {
        // uv layout: u[2][4][64] then v[2][4][64]
        int t = threadIdx.x;
        int h = t >> 6, k = t & 63;
        for (int i = 0; i < 2; ++i) {
            const float* Wr  = convs_W + (size_t)i * 64 * 256 + k * 256 + h * 64;
            const float* av  = convs_as + i * 256 + h * 64;
            const float* dv  = convs_ad + i * 256 + h * 64;
            float su = 0.f, sv = 0.f;
            for (int c = 0; c < 64; ++c) { su += Wr[c] * av[c]; sv += Wr[c] * dv[c]; }
            uv[i * 256 + h * 64 + k]       = su;
            uv[512 + i * 256 + h * 64 + k] = sv;
        }
    }
}

// ---------- MFMA bf16 GEMM for layer-0 xh (single pass over A, loop col-blocks) ----------
// C8[M,256] = fp8(A[M,128] @ W[128,256]) + per-head attention dots.
// grid (ceil(M/64)), block 256. A fragments held in registers across the 4 col-blocks.
__global__ __launch_bounds__(256)
void gemm_xh_mfma(const float* __restrict__ A, int lda,
                  const float* __restrict__ W, int Nc, int M, int K,
                  const float* __restrict__ att_s, const float* __restrict__ att_d,
                  float* __restrict__ as_out, float* __restrict__ ad_out,
                  unsigned char* __restrict__ C8)
{
    __shared__ short Wt[64 * 136];           // K=128 -> KP=136
    const int KP = K + 8;
    int tid  = threadIdx.x;
    int lane = tid & 63, wave = tid >> 6;
    int row0 = blockIdx.x * 64;
    int c15 = lane & 15, q = lane >> 4;

    int row = row0 + wave * 16 + c15;
    bool rok = row < M;
    const float* arow = A + (size_t)row * lda + q * 8;

    // load A fragments once (K=128 -> 4 bf16x8)
    bf16x8 avk[4];
    #pragma unroll
    for (int kk = 0; kk < 4; ++kk) {
        if (rok) {
            float4 a0 = *(const float4*)(arow + kk * 32);
            float4 a1 = *(const float4*)(arow + kk * 32 + 4);
            avk[kk][0] = f2bf(a0.x); avk[kk][1] = f2bf(a0.y);
            avk[kk][2] = f2bf(a0.z); avk[kk][3] = f2bf(a0.w);
            avk[kk][4] = f2bf(a1.x); avk[kk][5] = f2bf(a1.y);
            avk[kk][6] = f2bf(a1.z); avk[kk][7] = f2bf(a1.w);
        } else {
            avk[kk] = (bf16x8){0,0,0,0,0,0,0,0};
        }
    }

    for (int cb = 0; cb < 4; ++cb) {
        int colb = cb * 64;
        __syncthreads();
        {
            int n = tid & 63;
            for (int k = tid >> 6; k < K; k += 4)
                Wt[n * KP + k] = f2bf(W[(size_t)k * Nc + colb + n]);
        }
        __syncthreads();

        f32x4 acc[4];
        #pragma unroll
        for (int st = 0; st < 4; ++st) acc[st] = (f32x4){0.f, 0.f, 0.f, 0.f};

        #pragma unroll
        for (int kk = 0; kk < 4; ++kk) {
            #pragma unroll
            for (int st = 0; st < 4; ++st) {
                bf16x8 bv = *(const bf16x8*)(Wt + (st * 16 + c15) * KP + kk * 32 + q * 8);
                acc[st] = __builtin_amdgcn_mfma_f32_16x16x32_bf16(avk[kk], bv, acc[st], 0, 0, 0);
            }
        }

        #pragma unroll
        for (int r = 0; r < 4; ++r) {
            int orow = row0 + wave * 16 + q * 4 + r;
            if (orow >= M) continue;
            unsigned char* cb8 = C8 + (size_t)orow * 256 + colb + c15;
            #pragma unroll
            for (int st = 0; st < 4; ++st)
                cb8[st * 16] = f2fp8(acc[st][r]);
        }
        float sa[4], da[4];
        #pragma unroll
        for (int st = 0; st < 4; ++st) {
            sa[st] = att_s[colb + st * 16 + c15];
            da[st] = att_d[colb + st * 16 + c15];
        }
        #pragma unroll
        for (int r = 0; r < 4; ++r) {
            float ps = acc[0][r] * sa[0] + acc[1][r] * sa[1] + acc[2][r] * sa[2] + acc[3][r] * sa[3];
            float pd = acc[0][r] * da[0] + acc[1][r] * da[1] + acc[2][r] * da[2] + acc[3][r] * da[3];
            #pragma unroll
            for (int o = 1; o < 16; o <<= 1) {
                ps += __shfl_xor(ps, o);
                pd += __shfl_xor(pd, o);
            }
            int orow = row0 + wave * 16 + q * 4 + r;
            if (c15 == 0 && orow < M) {
                as_out[orow * 4 + cb] = ps;
                ad_out[orow * 4 + cb] = pd;
            }
        }
    }
}

// ---------- MFMA bf16 GEMM, Nc=64 ----------
// w_gat=1: W is convs_W (64,256) consumed as Wstack[(h,k),c]=W[k,h*64+c]
// fused epilogue options: scale, bias, BN+ELU (mode 1), +resid, fp8 h8 snapshot,
// as/ad logits via u/v (butterfly fold), fused attentional pooling via attW
// (block-reduced atomics: LDS tree -> 64 atomics per block per graph).
__global__ __launch_bounds__(256)
void gemm_n64_mfma(const void* __restrict__ Araw, int lda, int a_is_bf16,
                   const float* __restrict__ W, int w_gat, int M, int K,
                   const float* __restrict__ bias, float scale,
                   float* __restrict__ C, int ldc, int mode,
                   const float* __restrict__ bn_g, const float* __restrict__ bn_b,
                   const float* __restrict__ bn_m, const float* __restrict__ bn_v,
                   const float* __restrict__ resid, int ldr,
                   unsigned char* __restrict__ h8_out,
                   const float* __restrict__ u, const float* __restrict__ v,
                   float* __restrict__ as_out, float* __restrict__ ad_out,
                   const float* __restrict__ attW, const float* __restrict__ attb,
                   const int* __restrict__ batch,
                   float* __restrict__ hg_acc, float* __restrict__ wsum_acc)
{
    __shared__ short Wt[64 * 264];           // max K=256 -> KP=264 (reused as redbuf)
    const int KP = K + 8;
    int tid  = threadIdx.x;
    int lane = tid & 63, wave = tid >> 6;
    int row0 = blockIdx.x * 64;
    int c15 = lane & 15, q = lane >> 4;

    {
        int n = tid & 63;
        for (int k = tid >> 6; k < K; k += 4) {
            int widx = w_gat ? ((k & 63) * 256 + (k >> 6) * 64 + n) : (k * 64 + n);
            Wt[n * KP + k] = f2bf(W[widx]);
        }
    }
    __syncthreads();

    int row = row0 + wave * 16 + c15;
    bool rok = row < M;

    f32x4 acc[4];
    #pragma unroll
    for (int st = 0; st < 4; ++st) acc[st] = (f32x4){0.f, 0.f, 0.f, 0.f};

    for (int k0 = 0; k0 < K; k0 += 32) {
        bf16x8 av;
        if (rok) {
            if (a_is_bf16) {
                av = *(const bf16x8*)((const unsigned short*)Araw
                                      + (size_t)row * lda + k0 + q * 8);
            } else {
                const float* ap = (const float*)Araw + (size_t)row * lda + k0 + q * 8;
                float4 a0 = *(const float4*)ap;
                float4 a1 = *(const float4*)(ap + 4);
                av[0] = f2bf(a0.x); av[1] = f2bf(a0.y); av[2] = f2bf(a0.z); av[3] = f2bf(a0.w);
                av[4] = f2bf(a1.x); av[5] = f2bf(a1.y); av[6] = f2bf(a1.z); av[7] = f2bf(a1.w);
            }
        } else {
            av = (bf16x8){0,0,0,0,0,0,0,0};
        }
        #pragma unroll
        for (int st = 0; st < 4; ++st) {
            bf16x8 bv = *(const bf16x8*)(Wt + (st * 16 + c15) * KP + k0 + q * 8);
            acc[st] = __builtin_amdgcn_mfma_f32_16x16x32_bf16(av, bv, acc[st], 0, 0, 0);
        }
    }

    #pragma unroll
    for (int st = 0; st < 4; ++st) {
        int col = st * 16 + c15;
        float bs = bias ? bias[col] : 0.f;
        float sg = 1.f, sb = 0.f;
        if (mode == 1) {
            sg = bn_g[col] / sqrtf(bn_v[col] + BNEPS);
            sb = bn_b[col] - bn_m[col] * sg;
        }
        #pragma unroll
        for (int r = 0; r < 4; ++r) {
            int orow = row0 + wave * 16 + q * 4 + r;
            if (orow >= M) continue;
            float vvv = acc[st][r] * scale + bs;
            if (mode == 1) {
                vvv = vvv * sg + sb;
                vvv = vvv > 0.f ? vvv : __expf(vvv) - 1.f;
            }
            if (resid) vvv += resid[(size_t)orow * ldr + col];
            acc[st][r] = vvv;
            if (C) C[(size_t)orow * ldc + col] = vvv;
        }
    }

    if (h8_out) {
        #pragma unroll
        for (int r = 0; r < 4; ++r) {
            int orow = row0 + wave * 16 + q * 4 + r;
            if (orow >= M) continue;
            unsigned char* hb = h8_out + (size_t)orow * 64 + c15;
            #pragma unroll
            for (int st = 0; st < 4; ++st)
                hb[st * 16] = f2fp8(acc[st][r]);
        }
    }

    if (u) {
        float uu[4][4], vv2[4][4];
        #pragma unroll
        for (int h = 0; h < 4; ++h)
            #pragma unroll
            for (int st = 0; st < 4; ++st) {
                uu[h][st]  = u[h * 64 + st * 16 + c15];
                vv2[h][st] = v[h * 64 + st * 16 + c15];
            }
        #pragma unroll
        for (int r = 0; r < 4; ++r) {
            int orow = row0 + wave * 16 + q * 4 + r;
            float pv[8];
            #pragma unroll
            for (int h = 0; h < 4; ++h) {
                pv[h]     = acc[0][r] * uu[h][0] + acc[1][r] * uu[h][1]
                          + acc[2][r] * uu[h][2] + acc[3][r] * uu[h][3];
                pv[4 + h] = acc[0][r] * vv2[h][0] + acc[1][r] * vv2[h][1]
                          + acc[2][r] * vv2[h][2] + acc[3][r] * vv2[h][3];
            }
            #pragma unroll
            for (int j = 0; j < 4; ++j) {
                float send = (c15 & 8) ? pv[j] : pv[j + 4];
                float keep = (c15 & 8) ? pv[j + 4] : pv[j];
                pv[j] = keep + __shfl_xor(send, 8);
            }
            #pragma unroll
            for (int j = 0; j < 2; ++j) {
                float send = (c15 & 4) ? pv[j] : pv[j + 2];
                float keep = (c15 & 4) ? pv[j + 2] : pv[j];
                pv[j] = keep + __shfl_xor(send, 4);
            }
            {
                float send = (c15 & 2) ? pv[0] : pv[1];
                float keep = (c15 & 2) ? pv[1] : pv[0];
                pv[0] = keep + __shfl_xor(send, 2);
            }
            pv[0] += __shfl_xor(pv[0], 1);
            if ((c15 & 1) == 0 && orow < M) {
                int jj = c15 >> 1;
                if (jj < 4) as_out[orow * 4 + jj] = pv[0];
                else        ad_out[orow * 4 + (jj - 4)] = pv[0];
            }
        }
    }

    // ---- fused attentional pooling with block-level reduction ----
    if (attW) {
        float sa[4];
        #pragma unroll
        for (int st = 0; st < 4; ++st) sa[st] = attW[st * 16 + c15];
        float ab = attb[0];
        float wrow[4];
        int   grow[4];
        #pragma unroll
        for (int r = 0; r < 4; ++r) {
            int orow = row0 + wave * 16 + q * 4 + r;
            bool ok = orow < M;
            float ps = acc[0][r] * sa[0] + acc[1][r] * sa[1]
                     + acc[2][r] * sa[2] + acc[3][r] * sa[3];
            #pragma unroll
            for (int o = 1; o < 16; o <<= 1) ps += __shfl_xor(ps, o);
            wrow[r] = ok ? __expf(ps + ab) : 0.f;
            grow[r] = ok ? batch[orow] : -1;
        }
        int lastrow = row0 + 63; if (lastrow >= M) lastrow = M - 1;
        int gmin = batch[row0 < M ? row0 : M - 1];
        int gmax = batch[lastrow];
        float* red = (float*)Wt;   // [64][4] col-partials + [4] wsum partials
        __syncthreads();           // all waves done reading Wt
        for (int g = gmin; g <= gmax; ++g) {
            float cs[4] = {0.f, 0.f, 0.f, 0.f};
            float wsl = 0.f;
            #pragma unroll
            for (int r = 0; r < 4; ++r) {
                if (grow[r] == g) {
                    #pragma unroll
                    for (int st = 0; st < 4; ++st) cs[st] += acc[st][r] * wrow[r];
                    wsl += wrow[r];
                }
            }
            #pragma unroll
            for (int st = 0; st < 4; ++st) {
                cs[st] += __shfl_xor(cs[st], 16);
                cs[st] += __shfl_xor(cs[st], 32);
            }
            wsl += __shfl_xor(wsl, 16);
            wsl += __shfl_xor(wsl, 32);
            if (q == 0) {
                #pragma unroll
                for (int st = 0; st < 4; ++st)
                    red[(st * 16 + c15) * 4 + wave] = cs[st];
                if (c15 == 0) red[256 + wave] = wsl;
            }
            __syncthreads();
            if (tid < 64) {
                float vv = red[tid * 4] + red[tid * 4 + 1]
                         + red[tid * 4 + 2] + red[tid * 4 + 3];
                if (vv != 0.f) atomicAdd(&hg_acc[g * 64 + tid], vv);
            } else if (tid == 64) {
                float t = red[256] + red[257] + red[258] + red[259];
                if (t != 0.f) atomicAdd(&wsum_acc[g], t);
            }
            __syncthreads();
        }
    }
}

// ---------- CSR build: histogram over dst ----------
__global__ __launch_bounds__(256)
void hist_kernel(const int* __restrict__ ei, int E, int N, int* __restrict__ counts)
{
    int e = blockIdx.x * blockDim.x + threadIdx.x;
    int Etot = E + N;
    if (e >= Etot) return;
    int d = (e < E) ? ei[E + e] : e - E;
    atomicAdd(&counts[d], 1);
}

// ---------- scan phase 1: per-block partial sums ----------
__global__ __launch_bounds__(256)
void scan_phase1(const int* __restrict__ counts, int N, int* __restrict__ blocksum)
{
    __shared__ int wsum[4];
    int tid = threadIdx.x, lane = tid & 63, wave = tid >> 6;
    int base = blockIdx.x * SCAN_CHUNK;
    int s = 0;
    #pragma unroll
    for (int j = 0; j < SCAN_CHUNK / 256; ++j) {
        int idx = base + tid + j * 256;
        if (idx < N) s += counts[idx];
    }
    #pragma unroll
    for (int o = 32; o; o >>= 1) s += __shfl_xor(s, o);
    if (lane == 0) wsum[wave] = s;
    __syncthreads();
    if (tid == 0) blocksum[blockIdx.x] = wsum[0] + wsum[1] + wsum[2] + wsum[3];
}

// ---------- scan phase 3 (merged with global prefix of block sums) ----------
__global__ __launch_bounds__(256)
void scan_phase3(const int* __restrict__ counts, int N, int nb,
                 const int* __restrict__ blocksum,
                 int* __restrict__ rowptr, int* __restrict__ cursor)
{
    __shared__ int wsum[4];
    __shared__ int pref[64];
    int tid = threadIdx.x, lane = tid & 63, wave = tid >> 6;

    if (wave == 0) {
        int v = (lane < nb) ? blocksum[lane] : 0;
        int incl = v;
        #pragma unroll
        for (int o = 1; o < 64; o <<= 1) {
            int t = __shfl_up(incl, o);
            if (lane >= o) incl += t;
        }
        pref[lane] = incl;
    }
    __syncthreads();
    int boff = blockIdx.x ? pref[blockIdx.x - 1] : 0;
    if (blockIdx.x == 0 && tid == 0) rowptr[N] = pref[nb - 1];

    int start = blockIdx.x * SCAN_CHUNK + tid * 8;
    int v[8];
    int s = 0;
    #pragma unroll
    for (int j = 0; j < 8; ++j) {
        v[j] = (start + j < N) ? counts[start + j] : 0;
        s += v[j];
    }
    int incl = s;
    #pragma unroll
    for (int o = 1; o < 64; o <<= 1) {
        int t = __shfl_up(incl, o);
        if (lane >= o) incl += t;
    }
    if (lane == 63) wsum[wave] = incl;
    __syncthreads();
    int woff = 0;
    #pragma unroll
    for (int w = 0; w < 4; ++w) if (w < wave) woff += wsum[w];
    int run = boff + woff + incl - s;
    #pragma unroll
    for (int j = 0; j < 8; ++j) {
        int idx = start + j;
        if (idx < N) { rowptr[idx] = run; cursor[idx] = run; }
        run += v[j];
    }
}

// ---------- CSR build: scatter ----------
__global__ __launch_bounds__(256)
void scatter_kernel(const int* __restrict__ ei, int E, int N,
                    int* __restrict__ cursor, int* __restrict__ csr_src)
{
    int e = blockIdx.x * blockDim.x + threadIdx.x;
    int Etot = E + N;
    if (e >= Etot) return;
    int s, d;
    if (e < E) { s = ei[e]; d = ei[E + e]; } else { s = d = e - E; }
    int pos = atomicAdd(&cursor[d], 1);
    csr_src[pos] = s;
}

// ---------- layer-0 GAT aggregation (fp8 256-ch message gather) ----------
__global__ __launch_bounds__(256)
void aggregate_kernel(const int* __restrict__ rowptr, const int* __restrict__ csr_src,
                      const float* __restrict__ as_n, const float* __restrict__ ad_n,
                      const unsigned char* __restrict__ xh8,
                      const float* __restrict__ bias,
                      unsigned short* __restrict__ outp, int N)
{
    int node = (blockIdx.x * blockDim.x + threadIdx.x) >> 6;
    int lane = threadIdx.x & 63;
    if (node >= N) return;
    int h = lane >> 4, li = lane & 15, grp = lane & 48;
    int e0 = rowptr[node], e1 = rowptr[node + 1];
    float adh = ad_n[node * 4 + h];
    unsigned laneoff = (unsigned)(lane * 4);   // 4 fp8 bytes per lane

    float4 acc = make_float4(0.f, 0.f, 0.f, 0.f);
    float wsum = 0.f;

    for (int base = e0; base < e1; base += 16) {
        int cnt = e1 - base; if (cnt > 16) cnt = 16;
        int s = 0; float w = 0.f;
        if (li < cnt) {
            s = csr_src[base + li];
            float l = as_n[s * 4 + h] + adh;
            l = fmaxf(l, NEG * l);
            w = __expf(l);
        }
        int k = 0;
        for (; k + 3 < cnt; k += 4) {
            float w0 = __shfl(w, grp + k),     w1 = __shfl(w, grp + k + 1);
            float w2 = __shfl(w, grp + k + 2), w3 = __shfl(w, grp + k + 3);
            int s0 = __shfl(s, grp + k),       s1 = __shfl(s, grp + k + 1);
            int s2 = __shfl(s, grp + k + 2),   s3 = __shfl(s, grp + k + 3);
            unsigned x0 = *(const unsigned*)(xh8 + ((unsigned)s0 * 256u + laneoff));
            unsigned x1 = *(const unsigned*)(xh8 + ((unsigned)s1 * 256u + laneoff));
            unsigned x2 = *(const unsigned*)(xh8 + ((unsigned)s2 * 256u + laneoff));
            unsigned x3 = *(const unsigned*)(xh8 + ((unsigned)s3 * 256u + laneoff));
            f32x2 l0 = __builtin_amdgcn_cvt_pk_f32_fp8((int)x0, false);
            f32x2 h0 = __builtin_amdgcn_cvt_pk_f32_fp8((int)x0, true);
            f32x2 l1 = __builtin_amdgcn_cvt_pk_f32_fp8((int)x1, false);
            f32x2 h1 = __builtin_amdgcn_cvt_pk_f32_fp8((int)x1, true);
            f32x2 l2 = __builtin_amdgcn_cvt_pk_f32_fp8((int)x2, false);
            f32x2 h2 = __builtin_amdgcn_cvt_pk_f32_fp8((int)x2, true);
            f32x2 l3 = __builtin_amdgcn_cvt_pk_f32_fp8((int)x3, false);
            f32x2 h3 = __builtin_amdgcn_cvt_pk_f32_fp8((int)x3, true);
            acc.x += w0 * l0.x; acc.y += w0 * l0.y; acc.z += w0 * h0.x; acc.w += w0 * h0.y;
            acc.x += w1 * l1.x; acc.y += w1 * l1.y; acc.z += w1 * h1.x; acc.w += w1 * h1.y;
            acc.x += w2 * l2.x; acc.y += w2 * l2.y; acc.z += w2 * h2.x; acc.w += w2 * h2.y;
            acc.x += w3 * l3.x; acc.y += w3 * l3.y; acc.z += w3 * h3.x; acc.w += w3 * h3.y;
            wsum += (w0 + w1) + (w2 + w3);
        }
        for (; k < cnt; ++k) {
            float wk = __shfl(w, grp + k);
            int sk = __shfl(s, grp + k);
            unsigned xv = *(const unsigned*)(xh8 + ((unsigned)sk * 256u + laneoff));
            f32x2 lo = __builtin_amdgcn_cvt_pk_f32_fp8((int)xv, false);
            f32x2 hi = __builtin_amdgcn_cvt_pk_f32_fp8((int)xv, true);
            acc.x += wk * lo.x; acc.y += wk * lo.y;
            acc.z += wk * hi.x; acc.w += wk * hi.y;
            wsum += wk;
        }
    }

    float rw = 1.f / wsum;
    float4 bs = *(const float4*)(bias + lane * 4);
    ushort4 pk;
    pk.x = (unsigned short)f2bf(acc.x * rw + bs.x);
    pk.y = (unsigned short)f2bf(acc.y * rw + bs.y);
    pk.z = (unsigned short)f2bf(acc.z * rw + bs.z);
    pk.w = (unsigned short)f2bf(acc.w * rw + bs.w);
    *(ushort4*)(outp + (size_t)node * 256 + lane * 4) = pk;
}

// ---------- layers 1-2 aggregation: 64B fp8 rows, proven mapping ----------
__global__ __launch_bounds__(256)
void aggregate_z(const int* __restrict__ rowptr, const int* __restrict__ csr_src,
                 const float* __restrict__ as_n, const float* __restrict__ ad_n,
                 const unsigned char* __restrict__ h8,
                 unsigned short* __restrict__ zout, int N)
{
    int node = (blockIdx.x * blockDim.x + threadIdx.x) >> 6;
    int lane = threadIdx.x & 63;
    if (node >= N) return;
    int h = lane >> 4, li = lane & 15, grp = lane & 48;
    int e0 = rowptr[node], e1 = rowptr[node + 1];
    float adh = ad_n[node * 4 + h];
    unsigned laneoff = (unsigned)(li * 4);     // 4 fp8 bytes within the 64B row

    float4 acc = make_float4(0.f, 0.f, 0.f, 0.f);
    float wsum = 0.f;

    for (int base = e0; base < e1; base += 16) {
        int cnt = e1 - base; if (cnt > 16) cnt = 16;
        int s = 0; float w = 0.f;
        if (li < cnt) {
            s = csr_src[base + li];
            float l = as_n[s * 4 + h] + adh;
            l = fmaxf(l, NEG * l);
            w = __expf(l);
        }
        int k = 0;
        for (; k + 3 < cnt; k += 4) {
            float w0 = __shfl(w, grp + k),     w1 = __shfl(w, grp + k + 1);
            float w2 = __shfl(w, grp + k + 2), w3 = __shfl(w, grp + k + 3);
            int s0 = __shfl(s, grp + k),       s1 = __shfl(s, grp + k + 1);
            int s2 = __shfl(s, grp + k + 2),   s3 = __shfl(s, grp + k + 3);
            unsigned x0 = *(const unsigned*)(h8 + ((unsigned)s0 * 64u + laneoff));
            unsigned x1 = *(const unsigned*)(h8 + ((unsigned)s1 * 64u + laneoff));
            unsigned x2 = *(const unsigned*)(h8 + ((unsigned)s2 * 64u + laneoff));
            unsigned x3 = *(const unsigned*)(h8 + ((unsigned)s3 * 64u + laneoff));
            f32x2 l0 = __builtin_amdgcn_cvt_pk_f32_fp8((int)x0, false);
            f32x2 h0 = __builtin_amdgcn_cvt_pk_f32_fp8((int)x0, true);
            f32x2 l1 = __builtin_amdgcn_cvt_pk_f32_fp8((int)x1, false);
            f32x2 h1 = __builtin_amdgcn_cvt_pk_f32_fp8((int)x1, true);
            f32x2 l2 = __builtin_amdgcn_cvt_pk_f32_fp8((int)x2, false);
            f32x2 h2 = __builtin_amdgcn_cvt_pk_f32_fp8((int)x2, true);
            f32x2 l3 = __builtin_amdgcn_cvt_pk_f32_fp8((int)x3, false);
            f32x2 h3 = __builtin_amdgcn_cvt_pk_f32_fp8((int)x3, true);
            acc.x += w0 * l0.x; acc.y += w0 * l0.y; acc.z += w0 * h0.x; acc.w += w0 * h0.y;
            acc.x += w1 * l1.x; acc.y += w1 * l1.y; acc.z += w1 * h1.x; acc.w += w1 * h1.y;
            acc.x += w2 * l2.x; acc.y += w2 * l2.y; acc.z += w2 * h2.x; acc.w += w2 * h2.y;
            acc.x += w3 * l3.x; acc.y += w3 * l3.y; acc.z += w3 * h3.x; acc.w += w3 * h3.y;
            wsum += (w0 + w1) + (w2 + w3);
        }
        for (; k < cnt; ++k) {
            float wk = __shfl(w, grp + k);
            int sk = __shfl(s, grp + k);
            unsigned xv = *(const unsigned*)(h8 + ((unsigned)sk * 64u + laneoff));
            f32x2 lo = __builtin_amdgcn_cvt_pk_f32_fp8((int)xv, false);
            f32x2 hi = __builtin_amdgcn_cvt_pk_f32_fp8((int)xv, true);
            acc.x += wk * lo.x; acc.y += wk * lo.y;
            acc.z += wk * hi.x; acc.w += wk * hi.y;
            wsum += wk;
        }
    }

    float rw = 1.f / wsum;
    ushort4 pk;
    pk.x = (unsigned short)f2bf(acc.x * rw);
    pk.y = (unsigned short)f2bf(acc.y * rw);
    pk.z = (unsigned short)f2bf(acc.z * rw);
    pk.w = (unsigned short)f2bf(acc.w * rw);
    *(ushort4*)(zout + (size_t)node * 256 + h * 64 + li * 4) = pk;
}

// ---------- classifier head ----------
__global__ void cls_kernel(const float* __restrict__ hg_acc,
                           const float* __restrict__ wsum_acc,
                           const float* __restrict__ W1, const float* __restrict__ b1,
                           const float* __restrict__ W2, const float* __restrict__ b2,
                           float* __restrict__ out)
{
    int g = blockIdx.x, t = threadIdx.x;  // 32 threads
    __shared__ float z[32];
    __shared__ float h[64];
    float wsum = wsum_acc[g];
    float rw = (wsum > 0.f) ? 1.f / wsum : 0.f;
    h[t] = hg_acc[g * 64 + t] * rw;
    h[t + 32] = hg_acc[g * 64 + t + 32] * rw;
    __syncthreads();
    float acc = b1[t];
    for (int k = 0; k < 64; ++k) acc += h[k] * W1[k * 32 + t];
    z[t] = fmaxf(acc, 0.f);
    __syncthreads();
    if (t < 2) {
        float o = b2[t];
        for (int j = 0; j < 32; ++j) o += z[j] * W2[j * 2 + t];
        out[g * 2 + t] = o;
    }
}

extern "C" void kernel_launch(void* const* d_in, const int* in_sizes, int n_in,
                              void* d_out, int out_size, void* d_ws, size_t ws_size,
                              hipStream_t stream)
{
    const float* x        = (const float*)d_in[0];
    const int*   ei       = (const int*)d_in[1];
    const int*   batch    = (const int*)d_in[2];
    const float* conv0_W  = (const float*)d_in[3];
    const float* conv0_as = (const float*)d_in[4];
    const float* conv0_ad = (const float*)d_in[5];
    const float* conv0_b  = (const float*)d_in[6];
    const float* pre0_W   = (const float*)d_in[7];
    const float* pre0_b   = (const float*)d_in[8];
    const float* convs_W  = (const float*)d_in[9];
    const float* convs_as = (const float*)d_in[10];
    const float* convs_ad = (const float*)d_in[11];
    const float* convs_b  = (const float*)d_in[12];
    const float* bn_g     = (const float*)d_in[13];
    const float* bn_b     = (const float*)d_in[14];
    const float* bn_m     = (const float*)d_in[15];
    const float* bn_v     = (const float*)d_in[16];
    const float* jump_W   = (const float*)d_in[17];
    const float* jump_b   = (const float*)d_in[18];
    const float* att_W    = (const float*)d_in[19];
    const float* att_b    = (const float*)d_in[20];
    const float* cls_W1   = (const float*)d_in[21];
    const float* cls_b1   = (const float*)d_in[22];
    const float* cls_W2   = (const float*)d_in[23];
    const float* cls_b2   = (const float*)d_in[24];
    float* out = (float*)d_out;

    const int N = in_sizes[0] / 128;   // 50000
    const int E = in_sizes[1] / 2;     // 400000
    const int Etot = E + N;
    const int nb = (N + SCAN_CHUNK - 1) / SCAN_CHUNK;   // 25 <= 64

    // workspace layout
    float* ws      = (float*)d_ws;
    unsigned char* xh8      = (unsigned char*)ws;            // layer0: N*256 fp8; then h8a N*64 fp8 (aliased)
    unsigned short* h256_bf = (unsigned short*)ws + (size_t)N * 256;  // N*256 bf16 (L0 out_cat / z)
    float* repsAll = (float*)(h256_bf + (size_t)N * 256);   // N*192 f32
    float* as_n    = repsAll + (size_t)N * 192;             // N*4
    float* ad_n    = as_n + (size_t)N * 4;                  // N*4
    float* hg_acc  = ad_n + (size_t)N * 4;                  // 64*64
    float* wsum_acc= hg_acc + NGRAPH * 64;                  // 64
    int*   rowptr  = (int*)(wsum_acc + NGRAPH);             // N+1
    int*   cursor  = rowptr + (N + 1);                      // N
    int*   counts  = cursor + N;                            // N
    int*   csr_src = counts + N;                            // Etot
    int*   blocksum = csr_src + Etot;                       // 64
    float* uv      = (float*)(blocksum + 64);               // u[2][4][64]+v[2][4][64] = 1024
    float* as2     = uv + 1024;                             // N*4 (L2 logits)
    float* ad2     = as2 + (size_t)N * 4;                   // N*4
    unsigned char* h8b = (unsigned char*)(ad2 + (size_t)N * 4);  // N*64 fp8
    unsigned char* h8a = xh8;                               // N*64 fp8 (reuse xh8 region)

    dim3 blk(256);
    int node_wave_blocks = (N + 3) / 4;
    int edge_blocks      = (Etot + 255) / 256;
    int row_blocks       = (N + 63) / 64;

    // ---------------- init + CSR build ----------------
    init_kernel<<<64, blk, 0, stream>>>(batch, N, counts, hg_acc, wsum_acc,
                                        convs_W, convs_as, convs_ad, uv);
    hist_kernel<<<edge_blocks, blk, 0, stream>>>(ei, E, N, counts);
    scan_phase1<<<nb, blk, 0, stream>>>(counts, N, blocksum);
    scan_phase3<<<nb, blk, 0, stream>>>(counts, N, nb, blocksum, rowptr, cursor);
    scatter_kernel<<<edge_blocks, blk, 0, stream>>>(ei, E, N, cursor, csr_src);

    // ---------------- layer 0 ----------------
    {
        gemm_xh_mfma<<<row_blocks, blk, 0, stream>>>(x, 128, conv0_W, 256, N, 128,
                                                     conv0_as, conv0_ad, as_n, ad_n, xh8);
        aggregate_kernel<<<node_wave_blocks, blk, 0, stream>>>(
            rowptr, csr_src, as_n, ad_n, xh8, conv0_b, h256_bf, N);
        // pre0: h256 -> h1 (BN+ELU), fused: h8a snapshot + layer-1 as/ad logits
        gemm_n64_mfma<<<row_blocks, blk, 0, stream>>>(
            h256_bf, 256, 1, pre0_W, 0, N, 256, pre0_b, 1.f,
            repsAll, 192, 1, bn_g, bn_b, bn_m, bn_v,
            nullptr, 0, h8a, uv, uv + 512, as_n, ad_n,
            nullptr, nullptr, nullptr, nullptr, nullptr);
    }

    // ---------------- layer 1 ----------------
    aggregate_z<<<node_wave_blocks, blk, 0, stream>>>(rowptr, csr_src, as_n, ad_n,
                                                      h8a, h256_bf, N);
    gemm_n64_mfma<<<row_blocks, blk, 0, stream>>>(
        h256_bf, 256, 1, convs_W, 1, N, 256, convs_b, 0.25f,
        repsAll + 64, 192, 1, bn_g + 64, bn_b + 64, bn_m + 64, bn_v + 64,
        repsAll, 192, h8b, uv + 256, uv + 512 + 256, as2, ad2,
        nullptr, nullptr, nullptr, nullptr, nullptr);

    // ---------------- layer 2 ----------------
    aggregate_z<<<node_wave_blocks, blk, 0, stream>>>(rowptr, csr_src, as2, ad2,
                                                      h8b, h256_bf, N);
    gemm_n64_mfma<<<row_blocks, blk, 0, stream>>>(
        h256_bf, 256, 1, convs_W + (size_t)64 * 256, 1, N, 256, convs_b + 64, 0.25f,
        repsAll + 128, 192, 1, bn_g + 128, bn_b + 128, bn_m + 128, bn_v + 128,
        repsAll + 64, 192, nullptr, nullptr, nullptr, nullptr, nullptr,
        nullptr, nullptr, nullptr, nullptr, nullptr);

    // ---------------- JK projection + fused attentional pooling ----------------
    gemm_n64_mfma<<<row_blocks, blk, 0, stream>>>(
        repsAll, 192, 0, jump_W, 0, N, 192, jump_b, 1.f,
        nullptr, 64, 0, nullptr, nullptr, nullptr, nullptr,
        nullptr, 0, nullptr, nullptr, nullptr, nullptr, nullptr,
        att_W, att_b, batch, hg_acc, wsum_acc);

    // ---------------- classifier ----------------
    cls_kernel<<<NGRAPH, 32, 0, stream>>>(hg_acc, wsum_acc, cls_W1, cls_b1,
                                          cls_W2, cls_b2, out);
}

// Round 10
// 353.851 us; speedup vs baseline: 1.1383x; 1.0131x over previous
//
#include <hip/hip_runtime.h>
#include <hip/hip_bf16.h>
#include <math.h>

#define NEG 0.2f
#define BNEPS 1e-5f
#define NGRAPH 64
#define SCAN_CHUNK 2048

typedef short bf16x8 __attribute__((ext_vector_type(8)));            // 8 bf16 (4 VGPRs)
typedef float f32x4  __attribute__((ext_vector_type(4)));            // MFMA accumulator
typedef float f32x2  __attribute__((ext_vector_type(2)));            // fp8 cvt result

__device__ __forceinline__ float bf2f(unsigned short u) {
    return __uint_as_float(((unsigned)u) << 16);
}
__device__ __forceinline__ short f2bf(float f) {
    return (short)__bfloat16_as_ushort(__float2bfloat16(f));
}
__device__ __forceinline__ unsigned char f2fp8(float f) {
    // OCP e4m3 on gfx950; pack (f,f) and take low byte
    int pk = __builtin_amdgcn_cvt_pk_fp8_f32(f, f, 0, false);
    return (unsigned char)(pk & 0xFF);
}

// ---------- init: zero counts, pool accs; block 1: u/v = W_h @ att ----------
__global__ __launch_bounds__(256)
void init_kernel(const int* __restrict__ batch, int N,
                 int* __restrict__ counts,
                 float* __restrict__ hg_acc, float* __restrict__ wsum_acc,
                 const float* __restrict__ convs_W,
                 const float* __restrict__ convs_as, const float* __restrict__ convs_ad,
                 float* __restrict__ uv)
{
    int idx = blockIdx.x * 256 + threadIdx.x;
    for (int i = idx; i < N; i += gridDim.x * 256) counts[i] = 0;
    if (blockIdx.x == 0) {
        int t = threadIdx.x;
        for (int i = t; i < NGRAPH * 64; i += 256) hg_acc[i] = 0.f;
        if (t < NGRAPH) wsum_acc[t] = 0.f;
    }
    if (blockIdx.x == 1) {
        // uv layout: u[2][4][64] then v[2][4][64]
        int t = threadIdx.x;
        int h = t >> 6, k = t & 63;
        for (int i = 0; i < 2; ++i) {
            const float* Wr  = convs_W + (size_t)i * 64 * 256 + k * 256 + h * 64;
            const float* av  = convs_as + i * 256 + h * 64;
            const float* dv  = convs_ad + i * 256 + h * 64;
            float su = 0.f, sv = 0.f;
            for (int c = 0; c < 64; ++c) { su += Wr[c] * av[c]; sv += Wr[c] * dv[c]; }
            uv[i * 256 + h * 64 + k]       = su;
            uv[512 + i * 256 + h * 64 + k] = sv;
        }
    }
}

// ---------- MFMA bf16 GEMM for layer-0 xh: C8[M,256] = fp8(A @ W) + att dots ----------
__global__ __launch_bounds__(256)
void gemm_xh_mfma(const float* __restrict__ A, int lda,
                  const float* __restrict__ W, int Nc, int M, int K,
                  const float* __restrict__ att_s, const float* __restrict__ att_d,
                  float* __restrict__ as_out, float* __restrict__ ad_out,
                  unsigned char* __restrict__ C8)
{
    __shared__ short Wt[64 * 136];           // max K=128 -> KP=136
    const int KP = K + 8;
    int tid  = threadIdx.x;
    int lane = tid & 63, wave = tid >> 6;
    int row0 = blockIdx.x * 64;
    int colb = blockIdx.y * 64;
    int c15 = lane & 15, q = lane >> 4;

    {
        int n = tid & 63;
        for (int k = tid >> 6; k < K; k += 4)
            Wt[n * KP + k] = f2bf(W[(size_t)k * Nc + colb + n]);
    }
    __syncthreads();

    int row = row0 + wave * 16 + c15;
    bool rok = row < M;
    const float* arow = A + (size_t)row * lda + q * 8;

    f32x4 acc[4];
    #pragma unroll
    for (int st = 0; st < 4; ++st) acc[st] = (f32x4){0.f, 0.f, 0.f, 0.f};

    for (int k0 = 0; k0 < K; k0 += 32) {
        bf16x8 av;
        if (rok) {
            float4 a0 = *(const float4*)(arow + k0);
            float4 a1 = *(const float4*)(arow + k0 + 4);
            av[0] = f2bf(a0.x); av[1] = f2bf(a0.y); av[2] = f2bf(a0.z); av[3] = f2bf(a0.w);
            av[4] = f2bf(a1.x); av[5] = f2bf(a1.y); av[6] = f2bf(a1.z); av[7] = f2bf(a1.w);
        } else {
            av = (bf16x8){0,0,0,0,0,0,0,0};
        }
        #pragma unroll
        for (int st = 0; st < 4; ++st) {
            bf16x8 bv = *(const bf16x8*)(Wt + (st * 16 + c15) * KP + k0 + q * 8);
            acc[st] = __builtin_amdgcn_mfma_f32_16x16x32_bf16(av, bv, acc[st], 0, 0, 0);
        }
    }

    #pragma unroll
    for (int r = 0; r < 4; ++r) {
        int orow = row0 + wave * 16 + q * 4 + r;
        if (orow >= M) continue;
        unsigned char* cb = C8 + (size_t)orow * 256 + colb + c15;
        #pragma unroll
        for (int st = 0; st < 4; ++st)
            cb[st * 16] = f2fp8(acc[st][r]);
    }
    float sa[4], da[4];
    #pragma unroll
    for (int st = 0; st < 4; ++st) {
        sa[st] = att_s[colb + st * 16 + c15];
        da[st] = att_d[colb + st * 16 + c15];
    }
    #pragma unroll
    for (int r = 0; r < 4; ++r) {
        float ps = acc[0][r] * sa[0] + acc[1][r] * sa[1] + acc[2][r] * sa[2] + acc[3][r] * sa[3];
        float pd = acc[0][r] * da[0] + acc[1][r] * da[1] + acc[2][r] * da[2] + acc[3][r] * da[3];
        #pragma unroll
        for (int o = 1; o < 16; o <<= 1) {
            ps += __shfl_xor(ps, o);
            pd += __shfl_xor(pd, o);
        }
        int orow = row0 + wave * 16 + q * 4 + r;
        if (c15 == 0 && orow < M) {
            as_out[orow * 4 + blockIdx.y] = ps;
            ad_out[orow * 4 + blockIdx.y] = pd;
        }
    }
}

// ---------- MFMA bf16 GEMM, Nc=64 ----------
// w_gat=1: W is convs_W (64,256) consumed as Wstack[(h,k),c]=W[k,h*64+c]
// fused epilogue options: scale, bias, BN+ELU (mode 1), +resid, fp8 h8 snapshot,
// as/ad logits via u/v (butterfly fold), fused attentional pooling via attW
// (block-reduced atomics: LDS tree -> 64 atomics per block per graph).
__global__ __launch_bounds__(256)
void gemm_n64_mfma(const void* __restrict__ Araw, int lda, int a_is_bf16,
                   const float* __restrict__ W, int w_gat, int M, int K,
                   const float* __restrict__ bias, float scale,
                   float* __restrict__ C, int ldc, int mode,
                   const float* __restrict__ bn_g, const float* __restrict__ bn_b,
                   const float* __restrict__ bn_m, const float* __restrict__ bn_v,
                   const float* __restrict__ resid, int ldr,
                   unsigned char* __restrict__ h8_out,
                   const float* __restrict__ u, const float* __restrict__ v,
                   float* __restrict__ as_out, float* __restrict__ ad_out,
                   const float* __restrict__ attW, const float* __restrict__ attb,
                   const int* __restrict__ batch,
                   float* __restrict__ hg_acc, float* __restrict__ wsum_acc)
{
    __shared__ short Wt[64 * 264];           // max K=256 -> KP=264 (reused as redbuf)
    const int KP = K + 8;
    int tid  = threadIdx.x;
    int lane = tid & 63, wave = tid >> 6;
    int row0 = blockIdx.x * 64;
    int c15 = lane & 15, q = lane >> 4;

    {
        int n = tid & 63;
        for (int k = tid >> 6; k < K; k += 4) {
            int widx = w_gat ? ((k & 63) * 256 + (k >> 6) * 64 + n) : (k * 64 + n);
            Wt[n * KP + k] = f2bf(W[widx]);
        }
    }
    __syncthreads();

    int row = row0 + wave * 16 + c15;
    bool rok = row < M;

    f32x4 acc[4];
    #pragma unroll
    for (int st = 0; st < 4; ++st) acc[st] = (f32x4){0.f, 0.f, 0.f, 0.f};

    for (int k0 = 0; k0 < K; k0 += 32) {
        bf16x8 av;
        if (rok) {
            if (a_is_bf16) {
                av = *(const bf16x8*)((const unsigned short*)Araw
                                      + (size_t)row * lda + k0 + q * 8);
            } else {
                const float* ap = (const float*)Araw + (size_t)row * lda + k0 + q * 8;
                float4 a0 = *(const float4*)ap;
                float4 a1 = *(const float4*)(ap + 4);
                av[0] = f2bf(a0.x); av[1] = f2bf(a0.y); av[2] = f2bf(a0.z); av[3] = f2bf(a0.w);
                av[4] = f2bf(a1.x); av[5] = f2bf(a1.y); av[6] = f2bf(a1.z); av[7] = f2bf(a1.w);
            }
        } else {
            av = (bf16x8){0,0,0,0,0,0,0,0};
        }
        #pragma unroll
        for (int st = 0; st < 4; ++st) {
            bf16x8 bv = *(const bf16x8*)(Wt + (st * 16 + c15) * KP + k0 + q * 8);
            acc[st] = __builtin_amdgcn_mfma_f32_16x16x32_bf16(av, bv, acc[st], 0, 0, 0);
        }
    }

    #pragma unroll
    for (int st = 0; st < 4; ++st) {
        int col = st * 16 + c15;
        float bs = bias ? bias[col] : 0.f;
        float sg = 1.f, sb = 0.f;
        if (mode == 1) {
            sg = bn_g[col] / sqrtf(bn_v[col] + BNEPS);
            sb = bn_b[col] - bn_m[col] * sg;
        }
        #pragma unroll
        for (int r = 0; r < 4; ++r) {
            int orow = row0 + wave * 16 + q * 4 + r;
            if (orow >= M) continue;
            float vvv = acc[st][r] * scale + bs;
            if (mode == 1) {
                vvv = vvv * sg + sb;
                vvv = vvv > 0.f ? vvv : __expf(vvv) - 1.f;
            }
            if (resid) vvv += resid[(size_t)orow * ldr + col];
            acc[st][r] = vvv;
            if (C) C[(size_t)orow * ldc + col] = vvv;
        }
    }

    if (h8_out) {
        #pragma unroll
        for (int r = 0; r < 4; ++r) {
            int orow = row0 + wave * 16 + q * 4 + r;
            if (orow >= M) continue;
            unsigned char* hb = h8_out + (size_t)orow * 64 + c15;
            #pragma unroll
            for (int st = 0; st < 4; ++st)
                hb[st * 16] = f2fp8(acc[st][r]);
        }
    }

    if (u) {
        float uu[4][4], vv2[4][4];
        #pragma unroll
        for (int h = 0; h < 4; ++h)
            #pragma unroll
            for (int st = 0; st < 4; ++st) {
                uu[h][st]  = u[h * 64 + st * 16 + c15];
                vv2[h][st] = v[h * 64 + st * 16 + c15];
            }
        #pragma unroll
        for (int r = 0; r < 4; ++r) {
            int orow = row0 + wave * 16 + q * 4 + r;
            float pv[8];
            #pragma unroll
            for (int h = 0; h < 4; ++h) {
                pv[h]     = acc[0][r] * uu[h][0] + acc[1][r] * uu[h][1]
                          + acc[2][r] * uu[h][2] + acc[3][r] * uu[h][3];
                pv[4 + h] = acc[0][r] * vv2[h][0] + acc[1][r] * vv2[h][1]
                          + acc[2][r] * vv2[h][2] + acc[3][r] * vv2[h][3];
            }
            #pragma unroll
            for (int j = 0; j < 4; ++j) {
                float send = (c15 & 8) ? pv[j] : pv[j + 4];
                float keep = (c15 & 8) ? pv[j + 4] : pv[j];
                pv[j] = keep + __shfl_xor(send, 8);
            }
            #pragma unroll
            for (int j = 0; j < 2; ++j) {
                float send = (c15 & 4) ? pv[j] : pv[j + 2];
                float keep = (c15 & 4) ? pv[j + 2] : pv[j];
                pv[j] = keep + __shfl_xor(send, 4);
            }
            {
                float send = (c15 & 2) ? pv[0] : pv[1];
                float keep = (c15 & 2) ? pv[1] : pv[0];
                pv[0] = keep + __shfl_xor(send, 2);
            }
            pv[0] += __shfl_xor(pv[0], 1);
            if ((c15 & 1) == 0 && orow < M) {
                int jj = c15 >> 1;
                if (jj < 4) as_out[orow * 4 + jj] = pv[0];
                else        ad_out[orow * 4 + (jj - 4)] = pv[0];
            }
        }
    }

    // ---- fused attentional pooling with block-level reduction ----
    if (attW) {
        float sa[4];
        #pragma unroll
        for (int st = 0; st < 4; ++st) sa[st] = attW[st * 16 + c15];
        float ab = attb[0];
        float wrow[4];
        int   grow[4];
        #pragma unroll
        for (int r = 0; r < 4; ++r) {
            int orow = row0 + wave * 16 + q * 4 + r;
            bool ok = orow < M;
            float ps = acc[0][r] * sa[0] + acc[1][r] * sa[1]
                     + acc[2][r] * sa[2] + acc[3][r] * sa[3];
            #pragma unroll
            for (int o = 1; o < 16; o <<= 1) ps += __shfl_xor(ps, o);
            wrow[r] = ok ? __expf(ps + ab) : 0.f;
            grow[r] = ok ? batch[orow] : -1;
        }
        int lastrow = row0 + 63; if (lastrow >= M) lastrow = M - 1;
        int gmin = batch[row0 < M ? row0 : M - 1];
        int gmax = batch[lastrow];
        float* red = (float*)Wt;   // [64][4] col-partials + [4] wsum partials
        __syncthreads();           // all waves done reading Wt
        for (int g = gmin; g <= gmax; ++g) {
            float cs[4] = {0.f, 0.f, 0.f, 0.f};
            float wsl = 0.f;
            #pragma unroll
            for (int r = 0; r < 4; ++r) {
                if (grow[r] == g) {
                    #pragma unroll
                    for (int st = 0; st < 4; ++st) cs[st] += acc[st][r] * wrow[r];
                    wsl += wrow[r];
                }
            }
            #pragma unroll
            for (int st = 0; st < 4; ++st) {
                cs[st] += __shfl_xor(cs[st], 16);
                cs[st] += __shfl_xor(cs[st], 32);
            }
            wsl += __shfl_xor(wsl, 16);
            wsl += __shfl_xor(wsl, 32);
            if (q == 0) {
                #pragma unroll
                for (int st = 0; st < 4; ++st)
                    red[(st * 16 + c15) * 4 + wave] = cs[st];
                if (c15 == 0) red[256 + wave] = wsl;
            }
            __syncthreads();
            if (tid < 64) {
                float vv = red[tid * 4] + red[tid * 4 + 1]
                         + red[tid * 4 + 2] + red[tid * 4 + 3];
                if (vv != 0.f) atomicAdd(&hg_acc[g * 64 + tid], vv);
            } else if (tid == 64) {
                float t = red[256] + red[257] + red[258] + red[259];
                if (t != 0.f) atomicAdd(&wsum_acc[g], t);
            }
            __syncthreads();
        }
    }
}

// ---------- CSR build: histogram over dst ----------
__global__ __launch_bounds__(256)
void hist_kernel(const int* __restrict__ ei, int E, int N, int* __restrict__ counts)
{
    int e = blockIdx.x * blockDim.x + threadIdx.x;
    int Etot = E + N;
    if (e >= Etot) return;
    int d = (e < E) ? ei[E + e] : e - E;
    atomicAdd(&counts[d], 1);
}

// ---------- scan phase 1: per-block partial sums ----------
__global__ __launch_bounds__(256)
void scan_phase1(const int* __restrict__ counts, int N, int* __restrict__ blocksum)
{
    __shared__ int wsum[4];
    int tid = threadIdx.x, lane = tid & 63, wave = tid >> 6;
    int base = blockIdx.x * SCAN_CHUNK;
    int s = 0;
    #pragma unroll
    for (int j = 0; j < SCAN_CHUNK / 256; ++j) {
        int idx = base + tid + j * 256;
        if (idx < N) s += counts[idx];
    }
    #pragma unroll
    for (int o = 32; o; o >>= 1) s += __shfl_xor(s, o);
    if (lane == 0) wsum[wave] = s;
    __syncthreads();
    if (tid == 0) blocksum[blockIdx.x] = wsum[0] + wsum[1] + wsum[2] + wsum[3];
}

// ---------- scan phase 3 (merged with global prefix of block sums) ----------
__global__ __launch_bounds__(256)
void scan_phase3(const int* __restrict__ counts, int N, int nb,
                 const int* __restrict__ blocksum,
                 int* __restrict__ rowptr, int* __restrict__ cursor)
{
    __shared__ int wsum[4];
    __shared__ int pref[64];
    int tid = threadIdx.x, lane = tid & 63, wave = tid >> 6;

    if (wave == 0) {
        int v = (lane < nb) ? blocksum[lane] : 0;
        int incl = v;
        #pragma unroll
        for (int o = 1; o < 64; o <<= 1) {
            int t = __shfl_up(incl, o);
            if (lane >= o) incl += t;
        }
        pref[lane] = incl;
    }
    __syncthreads();
    int boff = blockIdx.x ? pref[blockIdx.x - 1] : 0;
    if (blockIdx.x == 0 && tid == 0) rowptr[N] = pref[nb - 1];

    int start = blockIdx.x * SCAN_CHUNK + tid * 8;
    int v[8];
    int s = 0;
    #pragma unroll
    for (int j = 0; j < 8; ++j) {
        v[j] = (start + j < N) ? counts[start + j] : 0;
        s += v[j];
    }
    int incl = s;
    #pragma unroll
    for (int o = 1; o < 64; o <<= 1) {
        int t = __shfl_up(incl, o);
        if (lane >= o) incl += t;
    }
    if (lane == 63) wsum[wave] = incl;
    __syncthreads();
    int woff = 0;
    #pragma unroll
    for (int w = 0; w < 4; ++w) if (w < wave) woff += wsum[w];
    int run = boff + woff + incl - s;
    #pragma unroll
    for (int j = 0; j < 8; ++j) {
        int idx = start + j;
        if (idx < N) { rowptr[idx] = run; cursor[idx] = run; }
        run += v[j];
    }
}

// ---------- CSR build: scatter ----------
__global__ __launch_bounds__(256)
void scatter_kernel(const int* __restrict__ ei, int E, int N,
                    int* __restrict__ cursor, int* __restrict__ csr_src)
{
    int e = blockIdx.x * blockDim.x + threadIdx.x;
    int Etot = E + N;
    if (e >= Etot) return;
    int s, d;
    if (e < E) { s = ei[e]; d = ei[E + e]; } else { s = d = e - E; }
    int pos = atomicAdd(&cursor[d], 1);
    csr_src[pos] = s;
}

// ---------- layer-0 GAT aggregation (fp8 256-ch message gather) ----------
__global__ __launch_bounds__(256)
void aggregate_kernel(const int* __restrict__ rowptr, const int* __restrict__ csr_src,
                      const float* __restrict__ as_n, const float* __restrict__ ad_n,
                      const unsigned char* __restrict__ xh8,
                      const float* __restrict__ bias,
                      unsigned short* __restrict__ outp, int N)
{
    int node = (blockIdx.x * blockDim.x + threadIdx.x) >> 6;
    int lane = threadIdx.x & 63;
    if (node >= N) return;
    int h = lane >> 4, li = lane & 15, grp = lane & 48;
    int e0 = rowptr[node], e1 = rowptr[node + 1];
    float adh = ad_n[node * 4 + h];
    unsigned laneoff = (unsigned)(lane * 4);   // 4 fp8 bytes per lane

    float4 acc = make_float4(0.f, 0.f, 0.f, 0.f);
    float wsum = 0.f;

    for (int base = e0; base < e1; base += 16) {
        int cnt = e1 - base; if (cnt > 16) cnt = 16;
        int s = 0; float w = 0.f;
        if (li < cnt) {
            s = csr_src[base + li];
            float l = as_n[s * 4 + h] + adh;
            l = fmaxf(l, NEG * l);
            w = __expf(l);
        }
        int k = 0;
        for (; k + 3 < cnt; k += 4) {
            float w0 = __shfl(w, grp + k),     w1 = __shfl(w, grp + k + 1);
            float w2 = __shfl(w, grp + k + 2), w3 = __shfl(w, grp + k + 3);
            int s0 = __shfl(s, grp + k),       s1 = __shfl(s, grp + k + 1);
            int s2 = __shfl(s, grp + k + 2),   s3 = __shfl(s, grp + k + 3);
            unsigned x0 = *(const unsigned*)(xh8 + ((unsigned)s0 * 256u + laneoff));
            unsigned x1 = *(const unsigned*)(xh8 + ((unsigned)s1 * 256u + laneoff));
            unsigned x2 = *(const unsigned*)(xh8 + ((unsigned)s2 * 256u + laneoff));
            unsigned x3 = *(const unsigned*)(xh8 + ((unsigned)s3 * 256u + laneoff));
            f32x2 l0 = __builtin_amdgcn_cvt_pk_f32_fp8((int)x0, false);
            f32x2 h0 = __builtin_amdgcn_cvt_pk_f32_fp8((int)x0, true);
            f32x2 l1 = __builtin_amdgcn_cvt_pk_f32_fp8((int)x1, false);
            f32x2 h1 = __builtin_amdgcn_cvt_pk_f32_fp8((int)x1, true);
            f32x2 l2 = __builtin_amdgcn_cvt_pk_f32_fp8((int)x2, false);
            f32x2 h2 = __builtin_amdgcn_cvt_pk_f32_fp8((int)x2, true);
            f32x2 l3 = __builtin_amdgcn_cvt_pk_f32_fp8((int)x3, false);
            f32x2 h3 = __builtin_amdgcn_cvt_pk_f32_fp8((int)x3, true);
            acc.x += w0 * l0.x; acc.y += w0 * l0.y; acc.z += w0 * h0.x; acc.w += w0 * h0.y;
            acc.x += w1 * l1.x; acc.y += w1 * l1.y; acc.z += w1 * h1.x; acc.w += w1 * h1.y;
            acc.x += w2 * l2.x; acc.y += w2 * l2.y; acc.z += w2 * h2.x; acc.w += w2 * h2.y;
            acc.x += w3 * l3.x; acc.y += w3 * l3.y; acc.z += w3 * h3.x; acc.w += w3 * h3.y;
            wsum += (w0 + w1) + (w2 + w3);
        }
        for (; k < cnt; ++k) {
            float wk = __shfl(w, grp + k);
            int sk = __shfl(s, grp + k);
            unsigned xv = *(const unsigned*)(xh8 + ((unsigned)sk * 256u + laneoff));
            f32x2 lo = __builtin_amdgcn_cvt_pk_f32_fp8((int)xv, false);
            f32x2 hi = __builtin_amdgcn_cvt_pk_f32_fp8((int)xv, true);
            acc.x += wk * lo.x; acc.y += wk * lo.y;
            acc.z += wk * hi.x; acc.w += wk * hi.y;
            wsum += wk;
        }
    }

    float rw = 1.f / wsum;
    float4 bs = *(const float4*)(bias + lane * 4);
    ushort4 pk;
    pk.x = (unsigned short)f2bf(acc.x * rw + bs.x);
    pk.y = (unsigned short)f2bf(acc.y * rw + bs.y);
    pk.z = (unsigned short)f2bf(acc.z * rw + bs.z);
    pk.w = (unsigned short)f2bf(acc.w * rw + bs.w);
    *(ushort4*)(outp + (size_t)node * 256 + lane * 4) = pk;
}

// ---------- layers 1-2 aggregation: 64B fp8 rows, proven mapping ----------
__global__ __launch_bounds__(256)
void aggregate_z(const int* __restrict__ rowptr, const int* __restrict__ csr_src,
                 const float* __restrict__ as_n, const float* __restrict__ ad_n,
                 const unsigned char* __restrict__ h8,
                 unsigned short* __restrict__ zout, int N)
{
    int node = (blockIdx.x * blockDim.x + threadIdx.x) >> 6;
    int lane = threadIdx.x & 63;
    if (node >= N) return;
    int h = lane >> 4, li = lane & 15, grp = lane & 48;
    int e0 = rowptr[node], e1 = rowptr[node + 1];
    float adh = ad_n[node * 4 + h];
    unsigned laneoff = (unsigned)(li * 4);     // 4 fp8 bytes within the 64B row

    float4 acc = make_float4(0.f, 0.f, 0.f, 0.f);
    float wsum = 0.f;

    for (int base = e0; base < e1; base += 16) {
        int cnt = e1 - base; if (cnt > 16) cnt = 16;
        int s = 0; float w = 0.f;
        if (li < cnt) {
            s = csr_src[base + li];
            float l = as_n[s * 4 + h] + adh;
            l = fmaxf(l, NEG * l);
            w = __expf(l);
        }
        int k = 0;
        for (; k + 3 < cnt; k += 4) {
            float w0 = __shfl(w, grp + k),     w1 = __shfl(w, grp + k + 1);
            float w2 = __shfl(w, grp + k + 2), w3 = __shfl(w, grp + k + 3);
            int s0 = __shfl(s, grp + k),       s1 = __shfl(s, grp + k + 1);
            int s2 = __shfl(s, grp + k + 2),   s3 = __shfl(s, grp + k + 3);
            unsigned x0 = *(const unsigned*)(h8 + ((unsigned)s0 * 64u + laneoff));
            unsigned x1 = *(const unsigned*)(h8 + ((unsigned)s1 * 64u + laneoff));
            unsigned x2 = *(const unsigned*)(h8 + ((unsigned)s2 * 64u + laneoff));
            unsigned x3 = *(const unsigned*)(h8 + ((unsigned)s3 * 64u + laneoff));
            f32x2 l0 = __builtin_amdgcn_cvt_pk_f32_fp8((int)x0, false);
            f32x2 h0 = __builtin_amdgcn_cvt_pk_f32_fp8((int)x0, true);
            f32x2 l1 = __builtin_amdgcn_cvt_pk_f32_fp8((int)x1, false);
            f32x2 h1 = __builtin_amdgcn_cvt_pk_f32_fp8((int)x1, true);
            f32x2 l2 = __builtin_amdgcn_cvt_pk_f32_fp8((int)x2, false);
            f32x2 h2 = __builtin_amdgcn_cvt_pk_f32_fp8((int)x2, true);
            f32x2 l3 = __builtin_amdgcn_cvt_pk_f32_fp8((int)x3, false);
            f32x2 h3 = __builtin_amdgcn_cvt_pk_f32_fp8((int)x3, true);
            acc.x += w0 * l0.x; acc.y += w0 * l0.y; acc.z += w0 * h0.x; acc.w += w0 * h0.y;
            acc.x += w1 * l1.x; acc.y += w1 * l1.y; acc.z += w1 * h1.x; acc.w += w1 * h1.y;
            acc.x += w2 * l2.x; acc.y += w2 * l2.y; acc.z += w2 * h2.x; acc.w += w2 * h2.y;
            acc.x += w3 * l3.x; acc.y += w3 * l3.y; acc.z += w3 * h3.x; acc.w += w3 * h3.y;
            wsum += (w0 + w1) + (w2 + w3);
        }
        for (; k < cnt; ++k) {
            float wk = __shfl(w, grp + k);
            int sk = __shfl(s, grp + k);
            unsigned xv = *(const unsigned*)(h8 + ((unsigned)sk * 64u + laneoff));
            f32x2 lo = __builtin_amdgcn_cvt_pk_f32_fp8((int)xv, false);
            f32x2 hi = __builtin_amdgcn_cvt_pk_f32_fp8((int)xv, true);
            acc.x += wk * lo.x; acc.y += wk * lo.y;
            acc.z += wk * hi.x; acc.w += wk * hi.y;
            wsum += wk;
        }
    }

    float rw = 1.f / wsum;
    ushort4 pk;
    pk.x = (unsigned short)f2bf(acc.x * rw);
    pk.y = (unsigned short)f2bf(acc.y * rw);
    pk.z = (unsigned short)f2bf(acc.z * rw);
    pk.w = (unsigned short)f2bf(acc.w * rw);
    *(ushort4*)(zout + (size_t)node * 256 + h * 64 + li * 4) = pk;
}

// ---------- classifier head ----------
__global__ void cls_kernel(const float* __restrict__ hg_acc,
                           const float* __restrict__ wsum_acc,
                           const float* __restrict__ W1, const float* __restrict__ b1,
                           const float* __restrict__ W2, const float* __restrict__ b2,
                           float* __restrict__ out)
{
    int g = blockIdx.x, t = threadIdx.x;  // 32 threads
    __shared__ float z[32];
    __shared__ float h[64];
    float wsum = wsum_acc[g];
    float rw = (wsum > 0.f) ? 1.f / wsum : 0.f;
    h[t] = hg_acc[g * 64 + t] * rw;
    h[t + 32] = hg_acc[g * 64 + t + 32] * rw;
    __syncthreads();
    float acc = b1[t];
    for (int k = 0; k < 64; ++k) acc += h[k] * W1[k * 32 + t];
    z[t] = fmaxf(acc, 0.f);
    __syncthreads();
    if (t < 2) {
        float o = b2[t];
        for (int j = 0; j < 32; ++j) o += z[j] * W2[j * 2 + t];
        out[g * 2 + t] = o;
    }
}

extern "C" void kernel_launch(void* const* d_in, const int* in_sizes, int n_in,
                              void* d_out, int out_size, void* d_ws, size_t ws_size,
                              hipStream_t stream)
{
    const float* x        = (const float*)d_in[0];
    const int*   ei       = (const int*)d_in[1];
    const int*   batch    = (const int*)d_in[2];
    const float* conv0_W  = (const float*)d_in[3];
    const float* conv0_as = (const float*)d_in[4];
    const float* conv0_ad = (const float*)d_in[5];
    const float* conv0_b  = (const float*)d_in[6];
    const float* pre0_W   = (const float*)d_in[7];
    const float* pre0_b   = (const float*)d_in[8];
    const float* convs_W  = (const float*)d_in[9];
    const float* convs_as = (const float*)d_in[10];
    const float* convs_ad = (const float*)d_in[11];
    const float* convs_b  = (const float*)d_in[12];
    const float* bn_g     = (const float*)d_in[13];
    const float* bn_b     = (const float*)d_in[14];
    const float* bn_m     = (const float*)d_in[15];
    const float* bn_v     = (const float*)d_in[16];
    const float* jump_W   = (const float*)d_in[17];
    const float* jump_b   = (const float*)d_in[18];
    const float* att_W    = (const float*)d_in[19];
    const float* att_b    = (const float*)d_in[20];
    const float* cls_W1   = (const float*)d_in[21];
    const float* cls_b1   = (const float*)d_in[22];
    const float* cls_W2   = (const float*)d_in[23];
    const float* cls_b2   = (const float*)d_in[24];
    float* out = (float*)d_out;

    const int N = in_sizes[0] / 128;   // 50000
    const int E = in_sizes[1] / 2;     // 400000
    const int Etot = E + N;
    const int nb = (N + SCAN_CHUNK - 1) / SCAN_CHUNK;   // 25 <= 64

    // workspace layout
    float* ws      = (float*)d_ws;
    unsigned char* xh8      = (unsigned char*)ws;            // layer0: N*256 fp8; then h8a N*64 fp8 (aliased)
    unsigned short* h256_bf = (unsigned short*)ws + (size_t)N * 256;  // N*256 bf16 (L0 out_cat / z)
    float* repsAll = (float*)(h256_bf + (size_t)N * 256);   // N*192 f32
    float* as_n    = repsAll + (size_t)N * 192;             // N*4
    float* ad_n    = as_n + (size_t)N * 4;                  // N*4
    float* hg_acc  = ad_n + (size_t)N * 4;                  // 64*64
    float* wsum_acc= hg_acc + NGRAPH * 64;                  // 64
    int*   rowptr  = (int*)(wsum_acc + NGRAPH);             // N+1
    int*   cursor  = rowptr + (N + 1);                      // N
    int*   counts  = cursor + N;                            // N
    int*   csr_src = counts + N;                            // Etot
    int*   blocksum = csr_src + Etot;                       // 64
    float* uv      = (float*)(blocksum + 64);               // u[2][4][64]+v[2][4][64] = 1024
    float* as2     = uv + 1024;                             // N*4 (L2 logits)
    float* ad2     = as2 + (size_t)N * 4;                   // N*4
    unsigned char* h8b = (unsigned char*)(ad2 + (size_t)N * 4);  // N*64 fp8
    unsigned char* h8a = xh8;                               // N*64 fp8 (reuse xh8 region)

    dim3 blk(256);
    int node_wave_blocks = (N + 3) / 4;
    int edge_blocks      = (Etot + 255) / 256;
    int row_blocks       = (N + 63) / 64;

    // ---------------- init + CSR build ----------------
    init_kernel<<<64, blk, 0, stream>>>(batch, N, counts, hg_acc, wsum_acc,
                                        convs_W, convs_as, convs_ad, uv);
    hist_kernel<<<edge_blocks, blk, 0, stream>>>(ei, E, N, counts);
    scan_phase1<<<nb, blk, 0, stream>>>(counts, N, blocksum);
    scan_phase3<<<nb, blk, 0, stream>>>(counts, N, nb, blocksum, rowptr, cursor);
    scatter_kernel<<<edge_blocks, blk, 0, stream>>>(ei, E, N, cursor, csr_src);

    // ---------------- layer 0 ----------------
    {
        dim3 g1(row_blocks, 4);
        gemm_xh_mfma<<<g1, blk, 0, stream>>>(x, 128, conv0_W, 256, N, 128,
                                             conv0_as, conv0_ad, as_n, ad_n, xh8);
        aggregate_kernel<<<node_wave_blocks, blk, 0, stream>>>(
            rowptr, csr_src, as_n, ad_n, xh8, conv0_b, h256_bf, N);
        // pre0: h256 -> h1 (BN+ELU), fused: h8a snapshot + layer-1 as/ad logits
        gemm_n64_mfma<<<row_blocks, blk, 0, stream>>>(
            h256_bf, 256, 1, pre0_W, 0, N, 256, pre0_b, 1.f,
            repsAll, 192, 1, bn_g, bn_b, bn_m, bn_v,
            nullptr, 0, h8a, uv, uv + 512, as_n, ad_n,
            nullptr, nullptr, nullptr, nullptr, nullptr);
    }

    // ---------------- layer 1 ----------------
    aggregate_z<<<node_wave_blocks, blk, 0, stream>>>(rowptr, csr_src, as_n, ad_n,
                                                      h8a, h256_bf, N);
    gemm_n64_mfma<<<row_blocks, blk, 0, stream>>>(
        h256_bf, 256, 1, convs_W, 1, N, 256, convs_b, 0.25f,
        repsAll + 64, 192, 1, bn_g + 64, bn_b + 64, bn_m + 64, bn_v + 64,
        repsAll, 192, h8b, uv + 256, uv + 512 + 256, as2, ad2,
        nullptr, nullptr, nullptr, nullptr, nullptr);

    // ---------------- layer 2 ----------------
    aggregate_z<<<node_wave_blocks, blk, 0, stream>>>(rowptr, csr_src, as2, ad2,
                                                      h8b, h256_bf, N);
    gemm_n64_mfma<<<row_blocks, blk, 0, stream>>>(
        h256_bf, 256, 1, convs_W + (size_t)64 * 256, 1, N, 256, convs_b + 64, 0.25f,
        repsAll + 128, 192, 1, bn_g + 128, bn_b + 128, bn_m + 128, bn_v + 128,
        repsAll + 64, 192, nullptr, nullptr, nullptr, nullptr, nullptr,
        nullptr, nullptr, nullptr, nullptr, nullptr);

    // ---------------- JK projection + fused attentional pooling ----------------
    gemm_n64_mfma<<<row_blocks, blk, 0, stream>>>(
        repsAll, 192, 0, jump_W, 0, N, 192, jump_b, 1.f,
        nullptr, 64, 0, nullptr, nullptr, nullptr, nullptr,
        nullptr, 0, nullptr, nullptr, nullptr, nullptr, nullptr,
        att_W, att_b, batch, hg_acc, wsum_acc);

    // ---------------- classifier ----------------
    cls_kernel<<<NGRAPH, 32, 0, stream>>>(hg_acc, wsum_acc, cls_W1, cls_b1,
                                          cls_W2, cls_b2, out);
}